// Round 1
// baseline (894.085 us; speedup 1.0000x reference)
//
#include <hip/hip_runtime.h>
#include <cstdint>

#define DEV __device__ __forceinline__

typedef __bf16 bf16x8 __attribute__((ext_vector_type(8)));
typedef float f32x4 __attribute__((ext_vector_type(4)));
typedef unsigned int u32;
typedef unsigned short u16;

DEV u16 f2bf(float f) {
  u32 u = __builtin_bit_cast(u32, f);
  u += 0x7fffu + ((u >> 16) & 1u);
  return (u16)(u >> 16);
}
DEV float bf2f(u16 b) { return __builtin_bit_cast(float, (u32)b << 16); }

// ---------------- conversion / packing ----------------
__global__ void cvt_f32_bf16(const float* __restrict__ in, u16* __restrict__ out, int n4) {
  int i = blockIdx.x * blockDim.x + threadIdx.x;
  if (i >= n4) return;
  float4 v = reinterpret_cast<const float4*>(in)[i];
  ushort4 o;
  o.x = f2bf(v.x); o.y = f2bf(v.y); o.z = f2bf(v.z); o.w = f2bf(v.w);
  reinterpret_cast<ushort4*>(out)[i] = o;
}

// Wc[oc][ic][3][3] f32 -> Bt[oc][(ky*3+kx)*256 + ic] bf16
__global__ void pack_conv_w(const float* __restrict__ w, u16* __restrict__ dst) {
  int j = blockIdx.x * blockDim.x + threadIdx.x;
  if (j >= 256 * 2304) return;
  int oc = j / 2304, r = j - oc * 2304;
  int slab = r >> 8, ic = r & 255;
  dst[j] = f2bf(w[(oc * 256 + ic) * 9 + slab]);
}

// ---------------- generic GEMM: C[M,N] = A[M,K] * Bt[N,K]^T ----------------
// 128x128 tile, BK=32, 256 threads = 4 waves (2x2), each wave 64x64 via 4x4 frags
template <int OUT_BF16, int DO_GELU>
__global__ __launch_bounds__(256, 2) void gemm_bt(
    const u16* __restrict__ A, int lda,
    const u16* __restrict__ Bt, int K,
    const float* __restrict__ bias,
    void* __restrict__ out, int ldo) {
  __shared__ __align__(16) u16 As[128 * 32];
  __shared__ __align__(16) u16 Bs[128 * 32];
  const int tid = threadIdx.x;
  const int wave = tid >> 6, lane = tid & 63;
  const int wr = (wave >> 1) * 64, wc = (wave & 1) * 64;
  const int lrow = lane & 15, kofs = (lane >> 4) * 8;
  const long rowbase = (long)blockIdx.x * 128;
  const int colbase = blockIdx.y * 128;
  const int sr = tid >> 2;
  const int sc = (tid & 3) * 8;

  const u16* A0 = A + (rowbase + sr) * (long)lda + sc;
  const u16* A1 = A + (rowbase + 64 + sr) * (long)lda + sc;
  const u16* B0 = Bt + (long)(colbase + sr) * K + sc;
  const u16* B1 = Bt + (long)(colbase + 64 + sr) * K + sc;

  f32x4 acc[4][4] = {};

  for (int k0 = 0; k0 < K; k0 += 32) {
    __syncthreads();
    *reinterpret_cast<uint4*>(&As[sr * 32 + sc]) = *reinterpret_cast<const uint4*>(A0 + k0);
    *reinterpret_cast<uint4*>(&As[(64 + sr) * 32 + sc]) = *reinterpret_cast<const uint4*>(A1 + k0);
    *reinterpret_cast<uint4*>(&Bs[sr * 32 + sc]) = *reinterpret_cast<const uint4*>(B0 + k0);
    *reinterpret_cast<uint4*>(&Bs[(64 + sr) * 32 + sc]) = *reinterpret_cast<const uint4*>(B1 + k0);
    __syncthreads();
    bf16x8 af[4], bfv[4];
#pragma unroll
    for (int m = 0; m < 4; ++m)
      af[m] = *reinterpret_cast<const bf16x8*>(&As[(wr + m * 16 + lrow) * 32 + kofs]);
#pragma unroll
    for (int n = 0; n < 4; ++n)
      bfv[n] = *reinterpret_cast<const bf16x8*>(&Bs[(wc + n * 16 + lrow) * 32 + kofs]);
#pragma unroll
    for (int m = 0; m < 4; ++m)
#pragma unroll
      for (int n = 0; n < 4; ++n)
        acc[m][n] = __builtin_amdgcn_mfma_f32_16x16x32_bf16(af[m], bfv[n], acc[m][n], 0, 0, 0);
  }

  const int r0 = (lane >> 4) * 4;
  const int occ = lane & 15;
#pragma unroll
  for (int m = 0; m < 4; ++m) {
#pragma unroll
    for (int n = 0; n < 4; ++n) {
      const int col = colbase + wc + n * 16 + occ;
      const float bv = bias ? bias[col] : 0.0f;
#pragma unroll
      for (int i = 0; i < 4; ++i) {
        const long row = rowbase + wr + m * 16 + r0 + i;
        float v = acc[m][n][i] + bv;
        if (DO_GELU) v = 0.5f * v * (1.0f + erff(v * 0.70710678118654752f));
        if (OUT_BF16)
          reinterpret_cast<u16*>(out)[row * ldo + col] = f2bf(v);
        else
          reinterpret_cast<float*>(out)[row * ldo + col] = v;
      }
    }
  }
}

// ---------------- 3x3 SAME conv as implicit GEMM (NHWC, W=128 rows per tile) ----------------
template <int OUT_BF16, int DO_GELU>
__global__ __launch_bounds__(256, 2) void conv3x3_gemm(
    const u16* __restrict__ V, int lda,   // NHWC activation base (channel 0 of block), row stride lda elems
    const u16* __restrict__ Bt,           // [256][2304]
    const float* __restrict__ bias,
    void* __restrict__ out, int ldo) {
  __shared__ __align__(16) u16 As[128 * 32];
  __shared__ __align__(16) u16 Bs[128 * 32];
  const int tid = threadIdx.x;
  const int wave = tid >> 6, lane = tid & 63;
  const int wr = (wave >> 1) * 64, wc = (wave & 1) * 64;
  const int lrow = lane & 15, kofs = (lane >> 4) * 8;
  const int pixbase = blockIdx.x * 128;
  const int b = pixbase >> 14;
  const int y = (pixbase >> 7) & 127;
  const int colbase = blockIdx.y * 128;
  const int sr = tid >> 2;
  const int sc = (tid & 3) * 8;
  const u16* B0 = Bt + (colbase + sr) * 2304 + sc;
  const u16* B1 = Bt + (colbase + 64 + sr) * 2304 + sc;

  f32x4 acc[4][4] = {};

  for (int k0 = 0; k0 < 2304; k0 += 32) {
    const int slab = k0 >> 8;  // 0..8
    const int ky = slab / 3 - 1;
    const int kx = slab % 3 - 1;
    const int c0 = k0 & 255;
    const int ysrc = y + ky;
    uint4 va = {0, 0, 0, 0}, vb = {0, 0, 0, 0};
    if (ysrc >= 0 && ysrc < 128) {
      const long rb = (long)b * 16384 + (long)ysrc * 128;
      const int xa = sr + kx;
      const int xb = 64 + sr + kx;
      if (xa >= 0 && xa < 128) va = *reinterpret_cast<const uint4*>(V + (rb + xa) * (long)lda + c0 + sc);
      if (xb < 128) vb = *reinterpret_cast<const uint4*>(V + (rb + xb) * (long)lda + c0 + sc);
    }
    __syncthreads();
    *reinterpret_cast<uint4*>(&As[sr * 32 + sc]) = va;
    *reinterpret_cast<uint4*>(&As[(64 + sr) * 32 + sc]) = vb;
    *reinterpret_cast<uint4*>(&Bs[sr * 32 + sc]) = *reinterpret_cast<const uint4*>(B0 + k0);
    *reinterpret_cast<uint4*>(&Bs[(64 + sr) * 32 + sc]) = *reinterpret_cast<const uint4*>(B1 + k0);
    __syncthreads();
    bf16x8 af[4], bfv[4];
#pragma unroll
    for (int m = 0; m < 4; ++m)
      af[m] = *reinterpret_cast<const bf16x8*>(&As[(wr + m * 16 + lrow) * 32 + kofs]);
#pragma unroll
    for (int n = 0; n < 4; ++n)
      bfv[n] = *reinterpret_cast<const bf16x8*>(&Bs[(wc + n * 16 + lrow) * 32 + kofs]);
#pragma unroll
    for (int m = 0; m < 4; ++m)
#pragma unroll
      for (int n = 0; n < 4; ++n)
        acc[m][n] = __builtin_amdgcn_mfma_f32_16x16x32_bf16(af[m], bfv[n], acc[m][n], 0, 0, 0);
  }

  const int r0 = (lane >> 4) * 4;
  const int occ = lane & 15;
#pragma unroll
  for (int m = 0; m < 4; ++m) {
#pragma unroll
    for (int n = 0; n < 4; ++n) {
      const int col = colbase + wc + n * 16 + occ;
      const float bv = bias[col];
#pragma unroll
      for (int i = 0; i < 4; ++i) {
        const long row = (long)pixbase + wr + m * 16 + r0 + i;
        float v = acc[m][n][i] + bv;
        if (DO_GELU) v = 0.5f * v * (1.0f + erff(v * 0.70710678118654752f));
        if (OUT_BF16)
          reinterpret_cast<u16*>(out)[row * ldo + col] = f2bf(v);
        else
          reinterpret_cast<float*>(out)[row * ldo + col] = v;
      }
    }
  }
}

// ---------------- per-(b,channel) sum of squares over n, for q and k cols (0..511) ----------------
__global__ void colsq_kernel(const u16* __restrict__ qkv, float* __restrict__ norm2) {
  const int chunk = blockIdx.x;  // 0..127 (128 rows each)
  const int b = blockIdx.y;
  const int t = threadIdx.x;  // 256 -> col pairs 0..511
  const u32* src = reinterpret_cast<const u32*>(qkv) + ((long)b * 16384 + (long)chunk * 128) * 384 + t;
  float a0 = 0.f, a1 = 0.f;
  for (int r = 0; r < 128; ++r) {
    const u32 v = src[(long)r * 384];
    const float f0 = bf2f((u16)(v & 0xffffu));
    const float f1 = bf2f((u16)(v >> 16));
    a0 += f0 * f0;
    a1 += f1 * f1;
  }
  atomicAdd(&norm2[b * 512 + 2 * t], a0);
  atomicAdd(&norm2[b * 512 + 2 * t + 1], a1);
}

// ---------------- G[b,h,d,e] = sum_n k[n,256+h*32+d] * q[n,h*32+e] ----------------
__global__ __launch_bounds__(256) void gram_kernel(const u16* __restrict__ qkv, float* __restrict__ G) {
  const int chunk = blockIdx.x;  // 8 chunks of 2048 rows
  const int bh = blockIdx.y;
  const int b = bh >> 3, h = bh & 7;
  __shared__ float kk[32][33];
  __shared__ float qq[32][33];
  const int tid = threadIdx.x;
  const int rr = tid >> 3;         // 0..31 : staging row, also d index
  const int c4 = (tid & 7) * 4;    // 0..28 : staging col group, also e group
  const long rowstart = (long)b * 16384 + (long)chunk * 2048;
  const u16* qp = qkv + rowstart * 768 + h * 32;
  const u16* kp = qp + 256;
  float acc0 = 0, acc1 = 0, acc2 = 0, acc3 = 0;
  for (int t0 = 0; t0 < 2048; t0 += 32) {
    __syncthreads();
    ushort4 kv = *reinterpret_cast<const ushort4*>(kp + (long)(t0 + rr) * 768 + c4);
    ushort4 qv = *reinterpret_cast<const ushort4*>(qp + (long)(t0 + rr) * 768 + c4);
    kk[rr][c4 + 0] = bf2f(kv.x); kk[rr][c4 + 1] = bf2f(kv.y);
    kk[rr][c4 + 2] = bf2f(kv.z); kk[rr][c4 + 3] = bf2f(kv.w);
    qq[rr][c4 + 0] = bf2f(qv.x); qq[rr][c4 + 1] = bf2f(qv.y);
    qq[rr][c4 + 2] = bf2f(qv.z); qq[rr][c4 + 3] = bf2f(qv.w);
    __syncthreads();
#pragma unroll
    for (int r = 0; r < 32; ++r) {
      const float kval = kk[r][rr];
      acc0 += kval * qq[r][c4 + 0];
      acc1 += kval * qq[r][c4 + 1];
      acc2 += kval * qq[r][c4 + 2];
      acc3 += kval * qq[r][c4 + 3];
    }
  }
  float* gp = G + ((long)bh * 32 + rr) * 32 + c4;
  atomicAdd(gp + 0, acc0); atomicAdd(gp + 1, acc1);
  atomicAdd(gp + 2, acc2); atomicAdd(gp + 3, acc3);
}

// ---------------- normalize + rescale + softmax over e ----------------
__global__ void attn_softmax(const float* __restrict__ G, const float* __restrict__ norm2,
                             const float* __restrict__ rescale, float* __restrict__ attn) {
  const int bh = blockIdx.x;
  const int b = bh >> 3, h = bh & 7;
  const int t = threadIdx.x;
  __shared__ float iqs[32], iks[32];
  if (t < 32) {
    iqs[t] = 1.0f / fmaxf(sqrtf(norm2[b * 512 + h * 32 + t]), 1e-12f);
    iks[t] = 1.0f / fmaxf(sqrtf(norm2[b * 512 + 256 + h * 32 + t]), 1e-12f);
  }
  __syncthreads();
  if (t < 32) {
    const float rs = rescale[h];
    const float ikd = iks[t] * rs;
    const float* gp = G + ((long)bh * 32 + t) * 32;
    float l[32];
    float mx = -1e30f;
#pragma unroll
    for (int e = 0; e < 32; ++e) {
      l[e] = gp[e] * ikd * iqs[e];
      mx = fmaxf(mx, l[e]);
    }
    float s = 0.f;
#pragma unroll
    for (int e = 0; e < 32; ++e) {
      l[e] = expf(l[e] - mx);
      s += l[e];
    }
    const float inv = 1.0f / s;
    float* op = attn + ((long)bh * 32 + t) * 32;
#pragma unroll
    for (int e = 0; e < 32; ++e) op[e] = l[e] * inv;
  }
}

// ---------------- xo[b,n,h*32+d] = sum_e attn[b,h,d,e] * v[b,n,h*32+e] ----------------
__global__ __launch_bounds__(256) void xo_apply(const u16* __restrict__ qkv,
                                                const float* __restrict__ attn,
                                                u16* __restrict__ xob) {
  const int blk = blockIdx.x;
  const int b = blk >> 8;
  const int pc = blk & 255;  // 64-pixel chunk
  const long nbase = (long)b * 16384 + (long)pc * 64;
  __shared__ float At[8 * 32 * 33];
  __shared__ __align__(16) u16 vs[8 * 256];
  const int t = threadIdx.x;
  for (int j = t; j < 8192; j += 256) {
    const int h = j >> 10, r = (j >> 5) & 31, e = j & 31;
    At[(h * 32 + r) * 33 + e] = attn[(long)b * 8192 + j];
  }
  const int h = t >> 5, d = t & 31;
  const float* Ar = &At[(h * 32 + d) * 33];
  for (int g = 0; g < 8; ++g) {
    __syncthreads();
    const u32* src = reinterpret_cast<const u32*>(qkv + (nbase + g * 8) * 768 + 512);
    u32* vsu = reinterpret_cast<u32*>(vs);
    for (int j = t; j < 1024; j += 256) {
      const int row = j >> 7, c = j & 127;
      vsu[j] = src[(long)row * 384 + c];
    }
    __syncthreads();
#pragma unroll
    for (int pp = 0; pp < 8; ++pp) {
      const u16* vr = vs + pp * 256 + h * 32;
      float a = 0.f;
#pragma unroll
      for (int e = 0; e < 32; ++e) a += Ar[e] * bf2f(vr[e]);
      xob[(nbase + g * 8 + pp) * 256 + t] = f2bf(a);
    }
  }
}

// ---------------- launch ----------------
extern "C" void kernel_launch(void* const* d_in, const int* in_sizes, int n_in,
                              void* d_out, int out_size, void* d_ws, size_t ws_size,
                              hipStream_t stream) {
  const float* x = (const float*)d_in[0];
  const float* Wq = (const float*)d_in[1];
  const float* Wk = (const float*)d_in[2];
  const float* Wv = (const float*)d_in[3];
  const float* resc = (const float*)d_in[4];
  const float* Wp = (const float*)d_in[5];
  const float* bp = (const float*)d_in[6];
  const float* Wc1 = (const float*)d_in[7];
  const float* bc1 = (const float*)d_in[8];
  const float* Wc2 = (const float*)d_in[9];
  const float* bc2 = (const float*)d_in[10];

  char* ws = (char*)d_ws;
  u16* qkv  = (u16*)(ws + 0L);           // [131072][768] bf16, q|k|v
  u16* xb   = (u16*)(ws + 201326592L);   // x bf16; later reused as conv1 output p1
  u16* xob  = (u16*)(ws + 268435456L);   // xo bf16
  u16* wqkv = (u16*)(ws + 335544320L);   // [768][256] bf16
  u16* wp   = (u16*)(ws + 335937536L);   // [256][256]
  u16* wc1r = (u16*)(ws + 336068608L);   // [256][2304]
  u16* wc2r = (u16*)(ws + 337248256L);   // [256][2304]
  float* norm2 = (float*)(ws + 338427904L);  // [8][512]
  float* G     = (float*)(ws + 338444288L);  // [8][8][32][32]
  float* attn  = (float*)(ws + 338706432L);  // [8][8][32][32]

  float* out_c = (float*)d_out;
  float* out_p = out_c + 33554432L;

  hipMemsetAsync(norm2, 0, 16384 + 262144, stream);

  cvt_f32_bf16<<<32768, 256, 0, stream>>>(x, xb, 8388608);
  cvt_f32_bf16<<<64, 256, 0, stream>>>(Wq, wqkv, 16384);
  cvt_f32_bf16<<<64, 256, 0, stream>>>(Wk, wqkv + 65536, 16384);
  cvt_f32_bf16<<<64, 256, 0, stream>>>(Wv, wqkv + 131072, 16384);
  cvt_f32_bf16<<<64, 256, 0, stream>>>(Wp, wp, 16384);
  pack_conv_w<<<2304, 256, 0, stream>>>(Wc1, wc1r);
  pack_conv_w<<<2304, 256, 0, stream>>>(Wc2, wc2r);

  // QKV projection: qkv[131072][768]
  gemm_bt<1, 0><<<dim3(1024, 6), 256, 0, stream>>>(xb, 256, wqkv, 256, nullptr, qkv, 768);

  colsq_kernel<<<dim3(128, 8), 256, 0, stream>>>(qkv, norm2);
  gram_kernel<<<dim3(8, 64), 256, 0, stream>>>(qkv, G);
  attn_softmax<<<64, 64, 0, stream>>>(G, norm2, resc, attn);
  xo_apply<<<2048, 256, 0, stream>>>(qkv, attn, xob);

  // out_c = xo @ Wp^T + bp
  gemm_bt<0, 0><<<dim3(1024, 2), 256, 0, stream>>>(xob, 256, wp, 256, bp, out_c, 256);

  // conv branch: p1 = gelu(conv1(v)), out_p = conv2(p1)
  conv3x3_gemm<1, 1><<<dim3(1024, 2), 256, 0, stream>>>(qkv + 512, 768, wc1r, bc1, xb, 256);
  conv3x3_gemm<0, 0><<<dim3(1024, 2), 256, 0, stream>>>(xb, 256, wc2r, bc2, out_p, 256);
}

// Round 2
// 806.084 us; speedup vs baseline: 1.1092x; 1.1092x over previous
//
#include <hip/hip_runtime.h>
#include <cstdint>

#define DEV __device__ __forceinline__

typedef __bf16 bf16x8 __attribute__((ext_vector_type(8)));
typedef float f32x4 __attribute__((ext_vector_type(4)));
typedef unsigned int u32;
typedef unsigned short u16;

DEV u16 f2bf(float f) {
  u32 u = __builtin_bit_cast(u32, f);
  u += 0x7fffu + ((u >> 16) & 1u);
  return (u16)(u >> 16);
}
DEV float bf2f(u16 b) { return __builtin_bit_cast(float, (u32)b << 16); }

// global -> LDS direct DMA, 16B per lane. LDS dest must be wave-uniform;
// HW writes lds_base + lane*16. Generic->AS3 via uintptr truncation (CK idiom).
DEV void gload16(const u16* g, u16* l) {
  __builtin_amdgcn_global_load_lds(
      (const __attribute__((address_space(1))) u32*)g,
      (__attribute__((address_space(3))) u32*)(uintptr_t)l, 16, 0, 0);
}

// ---------------- conversion / packing ----------------
__global__ void cvt_f32_bf16(const float* __restrict__ in, u16* __restrict__ out, int n4) {
  int i = blockIdx.x * blockDim.x + threadIdx.x;
  if (i >= n4) return;
  float4 v = reinterpret_cast<const float4*>(in)[i];
  ushort4 o;
  o.x = f2bf(v.x); o.y = f2bf(v.y); o.z = f2bf(v.z); o.w = f2bf(v.w);
  reinterpret_cast<ushort4*>(out)[i] = o;
}

// Wc[oc][ic][3][3] f32 -> Bt[oc][(ky*3+kx)*256 + ic] bf16
__global__ void pack_conv_w(const float* __restrict__ w, u16* __restrict__ dst) {
  int j = blockIdx.x * blockDim.x + threadIdx.x;
  if (j >= 256 * 2304) return;
  int oc = j / 2304, r = j - oc * 2304;
  int slab = r >> 8, ic = r & 255;
  dst[j] = f2bf(w[(oc * 256 + ic) * 9 + slab]);
}

// zero the 1-pixel halo of a [8][130][130][256] bf16 buffer
__global__ void border_zero(u16* __restrict__ p) {
  int idx = blockIdx.x * 256 + threadIdx.x;
  if (idx >= 8 * 516 * 32) return;
  int pix = idx >> 5, c8 = (idx & 31) << 3;
  int b = pix / 516, r = pix % 516;
  int x, y;
  if (r < 130)      { y = 0;   x = r; }
  else if (r < 260) { y = 129; x = r - 130; }
  else if (r < 388) { x = 0;   y = r - 259; }
  else              { x = 129; y = r - 387; }
  u16* dst = p + (((long)b * 130 + y) * 130 + x) * 256 + c8;
  *reinterpret_cast<uint4*>(dst) = uint4{0, 0, 0, 0};
}

// ---------------- GEMM: C[M,N] = A[M,K] * Bt[N,K]^T ----------------
// 128x256 tile, BK=32, 512 threads (8 waves 2x4), global_load_lds staging.
// EPI: 0 = f32 out (ldo), 2 = qkv-split (cols<512 -> qkvbuf[.,512], cols>=512 -> padded vp)
template <int EPI>
__global__ __launch_bounds__(512, 2) void gemm_bt2(
    const u16* __restrict__ A, int lda,
    const u16* __restrict__ Bt, int K,
    const float* __restrict__ bias,
    void* __restrict__ out, int ldo, u16* __restrict__ vp) {
  __shared__ __align__(16) u16 As[128 * 32];
  __shared__ __align__(16) u16 Bs[256 * 32];
  const int tid = threadIdx.x;
  const int wave = tid >> 6, lane = tid & 63;
  const int wr = (wave >> 2) * 64, wc = (wave & 3) * 64;
  const int lrow = lane & 15, kofs = (lane >> 4) * 8;
  int bx = blockIdx.x;
  bx = (bx & 7) * 128 + (bx >> 3);  // XCD-chunked swizzle (grid.x == 1024)
  const long rowbase = (long)bx * 128;
  const int colbase = blockIdx.y * 256;
  const int px = tid >> 2;
  const int sc = (tid & 3) * 8;
  const u16* abase = A + (rowbase + px) * (long)lda + sc;
  const u16* bbase = Bt + ((long)colbase + px) * K + sc;
  u16* asl = As + wave * 512;          // wave-uniform LDS bases (bytes: wave*1024)
  u16* bsl0 = Bs + wave * 512;
  u16* bsl1 = Bs + 4096 + wave * 512;

  f32x4 acc[4][4] = {};

  for (int k0 = 0; k0 < K; k0 += 32) {
    __syncthreads();
    gload16(abase + k0, asl);
    gload16(bbase + k0, bsl0);
    gload16(bbase + (long)128 * K + k0, bsl1);
    __syncthreads();
    bf16x8 af[4], bfv[4];
#pragma unroll
    for (int m = 0; m < 4; ++m)
      af[m] = *reinterpret_cast<const bf16x8*>(&As[(wr + m * 16 + lrow) * 32 + kofs]);
#pragma unroll
    for (int n = 0; n < 4; ++n)
      bfv[n] = *reinterpret_cast<const bf16x8*>(&Bs[(wc + n * 16 + lrow) * 32 + kofs]);
#pragma unroll
    for (int m = 0; m < 4; ++m)
#pragma unroll
      for (int n = 0; n < 4; ++n)
        acc[m][n] = __builtin_amdgcn_mfma_f32_16x16x32_bf16(af[m], bfv[n], acc[m][n], 0, 0, 0);
  }

  const int r0 = (lane >> 4) * 4;
  const int occ = lane & 15;
#pragma unroll
  for (int m = 0; m < 4; ++m) {
#pragma unroll
    for (int n = 0; n < 4; ++n) {
      const int col = colbase + wc + n * 16 + occ;
      float bv = (EPI == 0 && bias) ? bias[col] : 0.0f;
#pragma unroll
      for (int i = 0; i < 4; ++i) {
        const long row = rowbase + wr + m * 16 + r0 + i;
        float v = acc[m][n][i] + bv;
        if (EPI == 0) {
          reinterpret_cast<float*>(out)[row * ldo + col] = v;
        } else {  // qkv split
          if (col < 512) {
            reinterpret_cast<u16*>(out)[row * 512 + col] = f2bf(v);
          } else {
            const int b = (int)(row >> 14), rem = (int)(row & 16383);
            const int y = rem >> 7, x = rem & 127;
            vp[(((long)b * 130 + y + 1) * 130 + (x + 1)) * 256 + (col - 512)] = f2bf(v);
          }
        }
      }
    }
  }
}

// ---------------- 3x3 SAME conv, implicit GEMM over padded NHWC input ----------------
// input Vp: [8][130][130][256] bf16 zero-halo. 128x256 tile, K=2304.
// FIRST=1: gelu + bf16 out to padded buffer; FIRST=0: f32 out to linear buffer.
template <int FIRST>
__global__ __launch_bounds__(512, 2) void conv3x3(
    const u16* __restrict__ Vp, const u16* __restrict__ Bt,
    const float* __restrict__ bias, void* __restrict__ out) {
  __shared__ __align__(16) u16 As[128 * 32];
  __shared__ __align__(16) u16 Bs[256 * 32];
  const int tid = threadIdx.x;
  const int wave = tid >> 6, lane = tid & 63;
  const int wr = (wave >> 2) * 64, wc = (wave & 3) * 64;
  const int lrow = lane & 15, kofs = (lane >> 4) * 8;
  int bid = blockIdx.x;
  bid = (bid & 7) * 128 + (bid >> 3);  // XCD i owns image i (1024 blocks)
  const int b = bid >> 7, y = bid & 127;
  const int px = tid >> 2;
  const int sc = (tid & 3) * 8;
  const u16* abase = Vp + (((long)b * 130 + (y + 1)) * 130 + (px + 1)) * 256 + sc;
  const u16* bbase = Bt + (long)px * 2304 + sc;
  u16* asl = As + wave * 512;
  u16* bsl0 = Bs + wave * 512;
  u16* bsl1 = Bs + 4096 + wave * 512;

  f32x4 acc[4][4] = {};

  for (int k0 = 0; k0 < 2304; k0 += 32) {
    const int slab = k0 >> 8;            // 0..8 -> (ky,kx)
    const int ky = slab / 3 - 1, kx = slab % 3 - 1;
    const int c0 = k0 & 255;
    const long aofs = ((long)ky * 130 + kx) * 256 + c0;
    __syncthreads();
    gload16(abase + aofs, asl);
    gload16(bbase + k0, bsl0);
    gload16(bbase + (long)128 * 2304 + k0, bsl1);
    __syncthreads();
    bf16x8 af[4], bfv[4];
#pragma unroll
    for (int m = 0; m < 4; ++m)
      af[m] = *reinterpret_cast<const bf16x8*>(&As[(wr + m * 16 + lrow) * 32 + kofs]);
#pragma unroll
    for (int n = 0; n < 4; ++n)
      bfv[n] = *reinterpret_cast<const bf16x8*>(&Bs[(wc + n * 16 + lrow) * 32 + kofs]);
#pragma unroll
    for (int m = 0; m < 4; ++m)
#pragma unroll
      for (int n = 0; n < 4; ++n)
        acc[m][n] = __builtin_amdgcn_mfma_f32_16x16x32_bf16(af[m], bfv[n], acc[m][n], 0, 0, 0);
  }

  const int r0 = (lane >> 4) * 4;
  const int occ = lane & 15;
#pragma unroll
  for (int m = 0; m < 4; ++m) {
#pragma unroll
    for (int n = 0; n < 4; ++n) {
      const int col = wc + n * 16 + occ;
      const float bv = bias[col];
#pragma unroll
      for (int i = 0; i < 4; ++i) {
        const int xloc = wr + m * 16 + r0 + i;
        float v = acc[m][n][i] + bv;
        if (FIRST) {
          v = 0.5f * v * (1.0f + erff(v * 0.70710678118654752f));
          reinterpret_cast<u16*>(out)[(((long)b * 130 + y + 1) * 130 + (xloc + 1)) * 256 + col] = f2bf(v);
        } else {
          reinterpret_cast<float*>(out)[((long)bid * 128 + xloc) * 256 + col] = v;
        }
      }
    }
  }
}

// ---------------- per-(b,channel) sum of squares over n (qkv is [131072][512]) ----------------
__global__ void colsq_kernel(const u16* __restrict__ qkv, float* __restrict__ norm2) {
  const int chunk = blockIdx.x;  // 128 chunks of 128 rows
  const int b = blockIdx.y;
  const int t = threadIdx.x;  // 256 -> u32 col pairs
  const u32* src = reinterpret_cast<const u32*>(qkv) + ((long)b * 16384 + (long)chunk * 128) * 256 + t;
  float a0 = 0.f, a1 = 0.f;
  for (int r = 0; r < 128; ++r) {
    const u32 v = src[(long)r * 256];
    const float f0 = bf2f((u16)(v & 0xffffu));
    const float f1 = bf2f((u16)(v >> 16));
    a0 += f0 * f0;
    a1 += f1 * f1;
  }
  atomicAdd(&norm2[b * 512 + 2 * t], a0);
  atomicAdd(&norm2[b * 512 + 2 * t + 1], a1);
}

// ---------------- G[b,h,d,e] = sum_n k[n,256+h*32+d] * q[n,h*32+e] ----------------
__global__ __launch_bounds__(256) void gram_kernel(const u16* __restrict__ qkv, float* __restrict__ G) {
  const int chunk = blockIdx.x;  // 8 chunks of 2048 rows
  const int bh = blockIdx.y;
  const int b = bh >> 3, h = bh & 7;
  __shared__ float kk[32][33];
  __shared__ float qq[32][33];
  const int tid = threadIdx.x;
  const int rr = tid >> 3;
  const int c4 = (tid & 7) * 4;
  const long rowstart = (long)b * 16384 + (long)chunk * 2048;
  const u16* qp = qkv + rowstart * 512 + h * 32;
  const u16* kp = qp + 256;
  float acc0 = 0, acc1 = 0, acc2 = 0, acc3 = 0;
  for (int t0 = 0; t0 < 2048; t0 += 32) {
    __syncthreads();
    ushort4 kv = *reinterpret_cast<const ushort4*>(kp + (long)(t0 + rr) * 512 + c4);
    ushort4 qv = *reinterpret_cast<const ushort4*>(qp + (long)(t0 + rr) * 512 + c4);
    kk[rr][c4 + 0] = bf2f(kv.x); kk[rr][c4 + 1] = bf2f(kv.y);
    kk[rr][c4 + 2] = bf2f(kv.z); kk[rr][c4 + 3] = bf2f(kv.w);
    qq[rr][c4 + 0] = bf2f(qv.x); qq[rr][c4 + 1] = bf2f(qv.y);
    qq[rr][c4 + 2] = bf2f(qv.z); qq[rr][c4 + 3] = bf2f(qv.w);
    __syncthreads();
#pragma unroll
    for (int r = 0; r < 32; ++r) {
      const float kval = kk[r][rr];
      acc0 += kval * qq[r][c4 + 0];
      acc1 += kval * qq[r][c4 + 1];
      acc2 += kval * qq[r][c4 + 2];
      acc3 += kval * qq[r][c4 + 3];
    }
  }
  float* gp = G + ((long)bh * 32 + rr) * 32 + c4;
  atomicAdd(gp + 0, acc0); atomicAdd(gp + 1, acc1);
  atomicAdd(gp + 2, acc2); atomicAdd(gp + 3, acc3);
}

// ---------------- normalize + rescale + softmax over e ----------------
__global__ void attn_softmax(const float* __restrict__ G, const float* __restrict__ norm2,
                             const float* __restrict__ rescale, float* __restrict__ attn) {
  const int bh = blockIdx.x;
  const int b = bh >> 3, h = bh & 7;
  const int t = threadIdx.x;
  __shared__ float iqs[32], iks[32];
  if (t < 32) {
    iqs[t] = 1.0f / fmaxf(sqrtf(norm2[b * 512 + h * 32 + t]), 1e-12f);
    iks[t] = 1.0f / fmaxf(sqrtf(norm2[b * 512 + 256 + h * 32 + t]), 1e-12f);
  }
  __syncthreads();
  if (t < 32) {
    const float rs = rescale[h];
    const float ikd = iks[t] * rs;
    const float* gp = G + ((long)bh * 32 + t) * 32;
    float l[32];
    float mx = -1e30f;
#pragma unroll
    for (int e = 0; e < 32; ++e) {
      l[e] = gp[e] * ikd * iqs[e];
      mx = fmaxf(mx, l[e]);
    }
    float s = 0.f;
#pragma unroll
    for (int e = 0; e < 32; ++e) {
      l[e] = expf(l[e] - mx);
      s += l[e];
    }
    const float inv = 1.0f / s;
    float* op = attn + ((long)bh * 32 + t) * 32;
#pragma unroll
    for (int e = 0; e < 32; ++e) op[e] = l[e] * inv;
  }
}

// ---------------- xo[b,n,h*32+d] = sum_e attn[b,h,d,e] * v[b,n,h*32+e]; v from padded ----------------
__global__ __launch_bounds__(256) void xo_apply(const u16* __restrict__ vp,
                                                const float* __restrict__ attn,
                                                u16* __restrict__ xob) {
  const int blk = blockIdx.x;
  const int b = blk >> 8;
  const int pc = blk & 255;  // 64-pixel chunk
  const long nbase = (long)b * 16384 + (long)pc * 64;
  const int y = pc >> 1, x0 = (pc & 1) * 64;
  const u16* vrow = vp + (((long)b * 130 + y + 1) * 130 + x0 + 1) * 256;
  __shared__ float At[8 * 32 * 33];
  __shared__ __align__(16) u16 vs[8 * 256];
  const int t = threadIdx.x;
  for (int j = t; j < 8192; j += 256) {
    const int h = j >> 10, r = (j >> 5) & 31, e = j & 31;
    At[(h * 32 + r) * 33 + e] = attn[(long)b * 8192 + j];
  }
  const int h = t >> 5, d = t & 31;
  const float* Ar = &At[(h * 32 + d) * 33];
  for (int g = 0; g < 8; ++g) {
    __syncthreads();
    const u32* src = reinterpret_cast<const u32*>(vrow + (long)g * 8 * 256);
    u32* vsu = reinterpret_cast<u32*>(vs);
    for (int j = t; j < 1024; j += 256) {
      const int row = j >> 7, c = j & 127;
      vsu[j] = src[(long)row * 128 + c];
    }
    __syncthreads();
#pragma unroll
    for (int pp = 0; pp < 8; ++pp) {
      const u16* vr = vs + pp * 256 + h * 32;
      float a = 0.f;
#pragma unroll
      for (int e = 0; e < 32; ++e) a += Ar[e] * bf2f(vr[e]);
      xob[(nbase + g * 8 + pp) * 256 + t] = f2bf(a);
    }
  }
}

// ---------------- launch ----------------
extern "C" void kernel_launch(void* const* d_in, const int* in_sizes, int n_in,
                              void* d_out, int out_size, void* d_ws, size_t ws_size,
                              hipStream_t stream) {
  const float* x = (const float*)d_in[0];
  const float* Wq = (const float*)d_in[1];
  const float* Wk = (const float*)d_in[2];
  const float* Wv = (const float*)d_in[3];
  const float* resc = (const float*)d_in[4];
  const float* Wp = (const float*)d_in[5];
  const float* bp = (const float*)d_in[6];
  const float* Wc1 = (const float*)d_in[7];
  const float* bc1 = (const float*)d_in[8];
  const float* Wc2 = (const float*)d_in[9];
  const float* bc2 = (const float*)d_in[10];

  char* ws = (char*)d_ws;
  u16* qkv   = (u16*)(ws + 0L);            // [131072][512] q|k ; later reused as p1pad
  u16* p1pad = (u16*)(ws + 0L);            // [8][130][130][256] (conv1 out, after gram done)
  u16* vpad  = (u16*)(ws + 134217728L);    // [8][130][130][256] v padded
  u16* xb    = (u16*)(ws + 203440128L);    // x bf16 ; later reused as xob
  u16* xob   = (u16*)(ws + 203440128L);    // xo bf16 (after QKV gemm done)
  u16* wqkv  = (u16*)(ws + 270548992L);    // [768][256]
  u16* wp    = (u16*)(ws + 270942208L);    // [256][256]
  u16* wc1r  = (u16*)(ws + 271073280L);    // [256][2304]
  u16* wc2r  = (u16*)(ws + 272252928L);    // [256][2304]
  float* norm2 = (float*)(ws + 273432576L);  // [8][512]
  float* G     = (float*)(ws + 273448960L);  // [64][32][32]
  float* attn  = (float*)(ws + 273711104L);  // [64][32][32]

  float* out_c = (float*)d_out;
  float* out_p = out_c + 33554432L;

  hipMemsetAsync(norm2, 0, 16384 + 262144, stream);

  cvt_f32_bf16<<<32768, 256, 0, stream>>>(x, xb, 8388608);
  cvt_f32_bf16<<<64, 256, 0, stream>>>(Wq, wqkv, 16384);
  cvt_f32_bf16<<<64, 256, 0, stream>>>(Wk, wqkv + 65536, 16384);
  cvt_f32_bf16<<<64, 256, 0, stream>>>(Wv, wqkv + 131072, 16384);
  cvt_f32_bf16<<<64, 256, 0, stream>>>(Wp, wp, 16384);
  pack_conv_w<<<2304, 256, 0, stream>>>(Wc1, wc1r);
  pack_conv_w<<<2304, 256, 0, stream>>>(Wc2, wc2r);
  border_zero<<<516, 256, 0, stream>>>(vpad);

  // QKV projection: q,k -> qkv[131072][512]; v -> vpad (padded NHWC)
  gemm_bt2<2><<<dim3(1024, 3), 512, 0, stream>>>(xb, 256, wqkv, 256, nullptr, qkv, 512, vpad);

  colsq_kernel<<<dim3(128, 8), 256, 0, stream>>>(qkv, norm2);
  gram_kernel<<<dim3(8, 64), 256, 0, stream>>>(qkv, G);
  attn_softmax<<<64, 64, 0, stream>>>(G, norm2, resc, attn);
  xo_apply<<<2048, 256, 0, stream>>>(vpad, attn, xob);

  // out_c = xo @ Wp^T + bp
  gemm_bt2<0><<<dim3(1024, 1), 512, 0, stream>>>(xob, 256, wp, 256, bp, out_c, 256, nullptr);

  // conv branch (after out_c: p1pad overlays dead qkv)
  border_zero<<<516, 256, 0, stream>>>(p1pad);
  conv3x3<1><<<1024, 512, 0, stream>>>(vpad, wc1r, bc1, p1pad);
  conv3x3<0><<<1024, 512, 0, stream>>>(p1pad, wc2r, bc2, out_p);
}

// Round 3
// 757.559 us; speedup vs baseline: 1.1802x; 1.0641x over previous
//
#include <hip/hip_runtime.h>
#include <cstdint>

#define DEV __device__ __forceinline__

typedef __bf16 bf16x8 __attribute__((ext_vector_type(8)));
typedef float f32x4 __attribute__((ext_vector_type(4)));
typedef unsigned int u32;
typedef unsigned short u16;

DEV u16 f2bf(float f) {
  u32 u = __builtin_bit_cast(u32, f);
  u += 0x7fffu + ((u >> 16) & 1u);
  return (u16)(u >> 16);
}
DEV float bf2f(u16 b) { return __builtin_bit_cast(float, (u32)b << 16); }

// global -> LDS direct DMA, 16B per lane. LDS dest wave-uniform; HW adds lane*16.
DEV void gload16(const u16* g, u16* l) {
  __builtin_amdgcn_global_load_lds(
      (const __attribute__((address_space(1))) u32*)g,
      (__attribute__((address_space(3))) u32*)(uintptr_t)l, 16, 0, 0);
}

// ---------------- conversion / packing ----------------
__global__ void cvt_f32_bf16(const float* __restrict__ in, u16* __restrict__ out, int n4) {
  int i = blockIdx.x * blockDim.x + threadIdx.x;
  if (i >= n4) return;
  float4 v = reinterpret_cast<const float4*>(in)[i];
  ushort4 o;
  o.x = f2bf(v.x); o.y = f2bf(v.y); o.z = f2bf(v.z); o.w = f2bf(v.w);
  reinterpret_cast<ushort4*>(out)[i] = o;
}

// Wc[oc][ic][3][3] f32 -> Bt[oc][(ky*3+kx)*256 + ic] bf16
__global__ void pack_conv_w(const float* __restrict__ w, u16* __restrict__ dst) {
  int j = blockIdx.x * blockDim.x + threadIdx.x;
  if (j >= 256 * 2304) return;
  int oc = j / 2304, r = j - oc * 2304;
  int slab = r >> 8, ic = r & 255;
  dst[j] = f2bf(w[(oc * 256 + ic) * 9 + slab]);
}

// zero the 1-pixel halo of a [8][130][130][256] bf16 buffer
__global__ void border_zero(u16* __restrict__ p) {
  int idx = blockIdx.x * 256 + threadIdx.x;
  if (idx >= 8 * 516 * 32) return;
  int pix = idx >> 5, c8 = (idx & 31) << 3;
  int b = pix / 516, r = pix % 516;
  int x, y;
  if (r < 130)      { y = 0;   x = r; }
  else if (r < 260) { y = 129; x = r - 130; }
  else if (r < 388) { x = 0;   y = r - 259; }
  else              { x = 129; y = r - 387; }
  u16* dst = p + (((long)b * 130 + y) * 130 + x) * 256 + c8;
  *reinterpret_cast<uint4*>(dst) = uint4{0, 0, 0, 0};
}

// ================= 256x256 8-phase GEMM (T2+T3+T4+T5) =================
// C[M,256] = A[M,K] * Bt[256+,K]^T ; 512 thr = 8 waves (2Mx4N), BK=64.
// LDS 128KB dynamic: A[2][256][64] @0, B[2][256][64] @32768 (bf16 elems),
// 16B-slot XOR swizzle (slot ^= row&7) via pre-swizzled global source.
// CONV=1: A addressed as padded NHWC [8][130][130][256], M-tile = 2 image rows.
// EPI: 0 = qkv-split (q,k -> out[.,512]; v -> vp padded), 1 = f32+bias linear,
//      2 = gelu(+bias) -> bf16 padded.
template <int CONV, int KTOT, int EPI>
__global__ __launch_bounds__(512, 1) void mm8(
    const u16* __restrict__ A, const u16* __restrict__ Bt,
    const float* __restrict__ bias, void* __restrict__ out,
    u16* __restrict__ vp) {
  extern __shared__ u16 lds[];
  constexpr int NKT = KTOT / 64;
  constexpr int NITER = NKT / 2;
  const int tid = threadIdx.x;
  const int wave = tid >> 6, lane = tid & 63;
  const int wr = wave >> 2, wcid = wave & 3;
  const int lrow = lane & 15, lk = lane >> 4;
  int bid = (int)blockIdx.x;
  bid = (bid & 7) * 64 + (bid >> 3);  // XCD-chunked swizzle (grid.x == 512)
  const int colbase = blockIdx.y * 256;
  const long rowbase = (long)bid * 256;
  const int bimg = bid >> 6;
  const int y0 = (bid & 63) * 2;

  auto STAGE = [&](int kt, int isB, int half, int bufq) {
#pragma unroll
    for (int j = 0; j < 2; ++j) {
      const int idx = j * 512 + tid;
      const int rh = idx >> 3;                    // row within half (0..127)
      const int sg = (idx & 7) ^ (rh & 7);        // pre-swizzled global 16B slot
      const u16* g;
      if (isB) {
        g = Bt + (long)(colbase + half * 128 + rh) * KTOT + kt * 64 + sg * 8;
      } else if (CONV) {
        const int slab = kt >> 2;
        const int c0 = (kt & 3) * 64;
        const int ky = slab / 3 - 1, kx = slab - (slab / 3) * 3 - 1;
        g = A + (((long)bimg * 130 + (y0 + half) + 1 + ky) * 130 + (rh + 1 + kx)) * 256 + c0 + sg * 8;
      } else {
        g = A + (rowbase + half * 128 + rh) * (long)256 + kt * 64 + sg * 8;
      }
      u16* l = lds + (isB ? 32768 : 0) + bufq * 16384 + half * 8192 + (j * 512 + wave * 64) * 8;
      gload16(g, l);
    }
  };

  f32x4 acc[8][4] = {};
  bf16x8 bq[4][2];

  // prologue: t0.B0, t0.B1, t0.A0, t0.A1, t1.B0, t1.B1  (rota-consistent order)
  STAGE(0, 1, 0, 0); STAGE(0, 1, 1, 0);
  STAGE(0, 0, 0, 0); STAGE(0, 0, 1, 0);
  STAGE(1, 1, 0, 1); STAGE(1, 1, 1, 1);
  asm volatile("s_waitcnt vmcnt(4)" ::: "memory");
  __builtin_amdgcn_s_barrier();
  __builtin_amdgcn_sched_barrier(0);

  for (int it = 0; it < NITER; ++it) {
    const int u0 = 2 * it;
#pragma unroll
    for (int ph = 0; ph < 8; ++ph) {
      constexpr int S_ISB[8]  = {0, 0, 1, 1, 0, 0, 1, 1};
      constexpr int S_HALF[8] = {0, 1, 0, 1, 0, 1, 0, 1};
      constexpr int S_BUF[8]  = {1, 1, 0, 0, 0, 0, 1, 1};
      constexpr int S_DT[8]   = {1, 1, 2, 2, 2, 2, 3, 3};
      const int cbuf = ph >> 2, quad = ph & 3;
      if (quad == 0) {  // B frags once per K-tile (8 ds_read_b128)
#pragma unroll
        for (int nf = 0; nf < 4; ++nf)
#pragma unroll
          for (int ks = 0; ks < 2; ++ks) {
            const int n = wcid * 64 + nf * 16 + lrow;
            const int slot = (ks * 4 + lk) ^ (n & 7);
            bq[nf][ks] = *reinterpret_cast<const bf16x8*>(&lds[32768 + cbuf * 16384 + n * 64 + slot * 8]);
          }
      }
      bf16x8 aq[2][2];
#pragma unroll
      for (int mf = 0; mf < 2; ++mf)
#pragma unroll
        for (int ks = 0; ks < 2; ++ks) {
          const int r = wr * 128 + quad * 32 + mf * 16 + lrow;
          const int slot = (ks * 4 + lk) ^ (r & 7);
          aq[mf][ks] = *reinterpret_cast<const bf16x8*>(&lds[cbuf * 16384 + r * 64 + slot * 8]);
        }
      int st = u0 + S_DT[ph];
      if (st > NKT - 1) st = NKT - 1;  // epilogue dummy stages keep vmcnt counts exact
      STAGE(st, S_ISB[ph], S_HALF[ph], S_BUF[ph]);
      __builtin_amdgcn_s_barrier();
      asm volatile("s_waitcnt lgkmcnt(0)" ::: "memory");
      __builtin_amdgcn_sched_barrier(0);
      __builtin_amdgcn_s_setprio(1);
#pragma unroll
      for (int mf = 0; mf < 2; ++mf)
#pragma unroll
        for (int nf = 0; nf < 4; ++nf)
#pragma unroll
          for (int ks = 0; ks < 2; ++ks)
            acc[quad * 2 + mf][nf] = __builtin_amdgcn_mfma_f32_16x16x32_bf16(
                aq[mf][ks], bq[nf][ks], acc[quad * 2 + mf][nf], 0, 0, 0);
      __builtin_amdgcn_s_setprio(0);
      __builtin_amdgcn_sched_barrier(0);
      if (quad == 3)
        asm volatile("s_waitcnt vmcnt(4)" ::: "memory");  // counted, never 0
      __builtin_amdgcn_s_barrier();
      __builtin_amdgcn_sched_barrier(0);
    }
  }

  // -------- epilogue --------
  const int r0 = (lane >> 4) * 4;
  const int occ = lane & 15;
#pragma unroll
  for (int M = 0; M < 8; ++M) {
#pragma unroll
    for (int nf = 0; nf < 4; ++nf) {
      const int col = wcid * 64 + nf * 16 + occ;
#pragma unroll
      for (int i = 0; i < 4; ++i) {
        const int p = wr * 128 + M * 16 + r0 + i;  // local row 0..255
        float v = acc[M][nf][i];
        if (EPI == 0) {
          const long rowpix = rowbase + p;
          const int gcol = colbase + col;
          if (gcol < 512) {
            reinterpret_cast<u16*>(out)[rowpix * 512 + gcol] = f2bf(v);
          } else {
            const int b = (int)(rowpix >> 14), rem = (int)(rowpix & 16383);
            vp[(((long)b * 130 + (rem >> 7) + 1) * 130 + (rem & 127) + 1) * 256 + (gcol - 512)] = f2bf(v);
          }
        } else if (EPI == 1) {
          reinterpret_cast<float*>(out)[(rowbase + p) * 256 + col] = v + bias[col];
        } else {
          v += bias[col];
          v = 0.5f * v * (1.0f + erff(v * 0.70710678118654752f));
          const int y = y0 + (p >> 7), x = p & 127;
          reinterpret_cast<u16*>(out)[(((long)bimg * 130 + y + 1) * 130 + x + 1) * 256 + col] = f2bf(v);
        }
      }
    }
  }
}

// ---------------- per-(b,channel) sum of squares over n (qkv is [131072][512]) ----------------
__global__ void colsq_kernel(const u16* __restrict__ qkv, float* __restrict__ norm2) {
  const int chunk = blockIdx.x;
  const int b = blockIdx.y;
  const int t = threadIdx.x;
  const u32* src = reinterpret_cast<const u32*>(qkv) + ((long)b * 16384 + (long)chunk * 128) * 256 + t;
  float a0 = 0.f, a1 = 0.f;
  for (int r = 0; r < 128; ++r) {
    const u32 v = src[(long)r * 256];
    const float f0 = bf2f((u16)(v & 0xffffu));
    const float f1 = bf2f((u16)(v >> 16));
    a0 += f0 * f0;
    a1 += f1 * f1;
  }
  atomicAdd(&norm2[b * 512 + 2 * t], a0);
  atomicAdd(&norm2[b * 512 + 2 * t + 1], a1);
}

// ---------------- G[b,h,d,e] = sum_n k[n,256+h*32+d] * q[n,h*32+e] ----------------
__global__ __launch_bounds__(256) void gram_kernel(const u16* __restrict__ qkv, float* __restrict__ G) {
  const int chunk = blockIdx.x;
  const int bh = blockIdx.y;
  const int b = bh >> 3, h = bh & 7;
  __shared__ float kk[32][33];
  __shared__ float qq[32][33];
  const int tid = threadIdx.x;
  const int rr = tid >> 3;
  const int c4 = (tid & 7) * 4;
  const long rowstart = (long)b * 16384 + (long)chunk * 2048;
  const u16* qp = qkv + rowstart * 512 + h * 32;
  const u16* kp = qp + 256;
  float acc0 = 0, acc1 = 0, acc2 = 0, acc3 = 0;
  for (int t0 = 0; t0 < 2048; t0 += 32) {
    __syncthreads();
    ushort4 kv = *reinterpret_cast<const ushort4*>(kp + (long)(t0 + rr) * 512 + c4);
    ushort4 qv = *reinterpret_cast<const ushort4*>(qp + (long)(t0 + rr) * 512 + c4);
    kk[rr][c4 + 0] = bf2f(kv.x); kk[rr][c4 + 1] = bf2f(kv.y);
    kk[rr][c4 + 2] = bf2f(kv.z); kk[rr][c4 + 3] = bf2f(kv.w);
    qq[rr][c4 + 0] = bf2f(qv.x); qq[rr][c4 + 1] = bf2f(qv.y);
    qq[rr][c4 + 2] = bf2f(qv.z); qq[rr][c4 + 3] = bf2f(qv.w);
    __syncthreads();
#pragma unroll
    for (int r = 0; r < 32; ++r) {
      const float kval = kk[r][rr];
      acc0 += kval * qq[r][c4 + 0];
      acc1 += kval * qq[r][c4 + 1];
      acc2 += kval * qq[r][c4 + 2];
      acc3 += kval * qq[r][c4 + 3];
    }
  }
  float* gp = G + ((long)bh * 32 + rr) * 32 + c4;
  atomicAdd(gp + 0, acc0); atomicAdd(gp + 1, acc1);
  atomicAdd(gp + 2, acc2); atomicAdd(gp + 3, acc3);
}

// ---------------- normalize + rescale + softmax over e ----------------
__global__ void attn_softmax(const float* __restrict__ G, const float* __restrict__ norm2,
                             const float* __restrict__ rescale, float* __restrict__ attn) {
  const int bh = blockIdx.x;
  const int b = bh >> 3, h = bh & 7;
  const int t = threadIdx.x;
  __shared__ float iqs[32], iks[32];
  if (t < 32) {
    iqs[t] = 1.0f / fmaxf(sqrtf(norm2[b * 512 + h * 32 + t]), 1e-12f);
    iks[t] = 1.0f / fmaxf(sqrtf(norm2[b * 512 + 256 + h * 32 + t]), 1e-12f);
  }
  __syncthreads();
  if (t < 32) {
    const float rs = rescale[h];
    const float ikd = iks[t] * rs;
    const float* gp = G + ((long)bh * 32 + t) * 32;
    float l[32];
    float mx = -1e30f;
#pragma unroll
    for (int e = 0; e < 32; ++e) {
      l[e] = gp[e] * ikd * iqs[e];
      mx = fmaxf(mx, l[e]);
    }
    float s = 0.f;
#pragma unroll
    for (int e = 0; e < 32; ++e) {
      l[e] = expf(l[e] - mx);
      s += l[e];
    }
    const float inv = 1.0f / s;
    float* op = attn + ((long)bh * 32 + t) * 32;
#pragma unroll
    for (int e = 0; e < 32; ++e) op[e] = l[e] * inv;
  }
}

// ---------------- xo[b,n,h*32+d] = sum_e attn[b,h,d,e] * v[b,n,h*32+e]; v from padded ----------------
__global__ __launch_bounds__(256) void xo_apply(const u16* __restrict__ vp,
                                                const float* __restrict__ attn,
                                                u16* __restrict__ xob) {
  const int blk = blockIdx.x;
  const int b = blk >> 8;
  const int pc = blk & 255;
  const long nbase = (long)b * 16384 + (long)pc * 64;
  const int y = pc >> 1, x0 = (pc & 1) * 64;
  const u16* vrow = vp + (((long)b * 130 + y + 1) * 130 + x0 + 1) * 256;
  __shared__ float At[8 * 32 * 33];
  __shared__ __align__(16) u16 vs[8 * 256];
  const int t = threadIdx.x;
  for (int j = t; j < 8192; j += 256) {
    const int h = j >> 10, r = (j >> 5) & 31, e = j & 31;
    At[(h * 32 + r) * 33 + e] = attn[(long)b * 8192 + j];
  }
  const int h = t >> 5, d = t & 31;
  const float* Ar = &At[(h * 32 + d) * 33];
  for (int g = 0; g < 8; ++g) {
    __syncthreads();
    const u32* src = reinterpret_cast<const u32*>(vrow + (long)g * 8 * 256);
    u32* vsu = reinterpret_cast<u32*>(vs);
    for (int j = t; j < 1024; j += 256) {
      const int row = j >> 7, c = j & 127;
      vsu[j] = src[(long)row * 128 + c];
    }
    __syncthreads();
#pragma unroll
    for (int pp = 0; pp < 8; ++pp) {
      const u16* vr = vs + pp * 256 + h * 32;
      float a = 0.f;
#pragma unroll
      for (int e = 0; e < 32; ++e) a += Ar[e] * bf2f(vr[e]);
      xob[(nbase + g * 8 + pp) * 256 + t] = f2bf(a);
    }
  }
}

// ---------------- launch ----------------
extern "C" void kernel_launch(void* const* d_in, const int* in_sizes, int n_in,
                              void* d_out, int out_size, void* d_ws, size_t ws_size,
                              hipStream_t stream) {
  const float* x = (const float*)d_in[0];
  const float* Wq = (const float*)d_in[1];
  const float* Wk = (const float*)d_in[2];
  const float* Wv = (const float*)d_in[3];
  const float* resc = (const float*)d_in[4];
  const float* Wp = (const float*)d_in[5];
  const float* bp = (const float*)d_in[6];
  const float* Wc1 = (const float*)d_in[7];
  const float* bc1 = (const float*)d_in[8];
  const float* Wc2 = (const float*)d_in[9];
  const float* bc2 = (const float*)d_in[10];

  char* ws = (char*)d_ws;
  u16* qkv   = (u16*)(ws + 0L);            // [131072][512] q|k ; later reused as p1pad
  u16* p1pad = (u16*)(ws + 0L);            // [8][130][130][256] (conv1 out, after gram done)
  u16* vpad  = (u16*)(ws + 134217728L);    // [8][130][130][256] v padded
  u16* xb    = (u16*)(ws + 203440128L);    // x bf16 ; later reused as xob
  u16* xob   = (u16*)(ws + 203440128L);    // xo bf16 (after QKV gemm done)
  u16* wqkv  = (u16*)(ws + 270548992L);    // [768][256]
  u16* wp    = (u16*)(ws + 270942208L);    // [256][256]
  u16* wc1r  = (u16*)(ws + 271073280L);    // [256][2304]
  u16* wc2r  = (u16*)(ws + 272252928L);    // [256][2304]
  float* norm2 = (float*)(ws + 273432576L);  // [8][512]
  float* G     = (float*)(ws + 273448960L);  // [64][32][32]
  float* attn  = (float*)(ws + 273711104L);  // [64][32][32]

  float* out_c = (float*)d_out;
  float* out_p = out_c + 33554432L;

  hipMemsetAsync(norm2, 0, 16384 + 262144, stream);

  cvt_f32_bf16<<<32768, 256, 0, stream>>>(x, xb, 8388608);
  cvt_f32_bf16<<<64, 256, 0, stream>>>(Wq, wqkv, 16384);
  cvt_f32_bf16<<<64, 256, 0, stream>>>(Wk, wqkv + 65536, 16384);
  cvt_f32_bf16<<<64, 256, 0, stream>>>(Wv, wqkv + 131072, 16384);
  cvt_f32_bf16<<<64, 256, 0, stream>>>(Wp, wp, 16384);
  pack_conv_w<<<2304, 256, 0, stream>>>(Wc1, wc1r);
  pack_conv_w<<<2304, 256, 0, stream>>>(Wc2, wc2r);
  border_zero<<<516, 256, 0, stream>>>(vpad);

  // QKV projection: q,k -> qkv[131072][512]; v -> vpad (padded NHWC)
  mm8<0, 256, 0><<<dim3(512, 3), 512, 131072, stream>>>(xb, wqkv, nullptr, qkv, vpad);

  colsq_kernel<<<dim3(128, 8), 256, 0, stream>>>(qkv, norm2);
  gram_kernel<<<dim3(8, 64), 256, 0, stream>>>(qkv, G);
  attn_softmax<<<64, 64, 0, stream>>>(G, norm2, resc, attn);
  xo_apply<<<2048, 256, 0, stream>>>(vpad, attn, xob);

  // out_c = xo @ Wp^T + bp
  mm8<0, 256, 1><<<dim3(512, 1), 512, 131072, stream>>>(xob, wp, bp, out_c, nullptr);

  // conv branch (after out_c: p1pad overlays dead qkv)
  border_zero<<<516, 256, 0, stream>>>(p1pad);
  mm8<1, 2304, 2><<<dim3(512, 1), 512, 131072, stream>>>(vpad, wc1r, bc1, p1pad, nullptr);
  mm8<1, 2304, 1><<<dim3(512, 1), 512, 131072, stream>>>(p1pad, wc2r, bc2, out_p, nullptr);
}

// Round 4
// 733.549 us; speedup vs baseline: 1.2188x; 1.0327x over previous
//
#include <hip/hip_runtime.h>
#include <cstdint>

#define DEV __device__ __forceinline__

typedef __bf16 bf16x8 __attribute__((ext_vector_type(8)));
typedef float f32x4 __attribute__((ext_vector_type(4)));
typedef unsigned int u32;
typedef unsigned short u16;

DEV u16 f2bf(float f) {
  u32 u = __builtin_bit_cast(u32, f);
  u += 0x7fffu + ((u >> 16) & 1u);
  return (u16)(u >> 16);
}
DEV float bf2f(u16 b) { return __builtin_bit_cast(float, (u32)b << 16); }

// global -> LDS direct DMA, 16B per lane. LDS dest wave-uniform; HW adds lane*16.
DEV void gload16(const u16* g, u16* l) {
  __builtin_amdgcn_global_load_lds(
      (const __attribute__((address_space(1))) u32*)g,
      (__attribute__((address_space(3))) u32*)(uintptr_t)l, 16, 0, 0);
}

// zero the 1-pixel halo of a [8][130][130][256] bf16 buffer; idx < 8*516*32
DEV void border_body(u16* __restrict__ p, int idx) {
  int pix = idx >> 5, c8 = (idx & 31) << 3;
  int b = pix / 516, r = pix % 516;
  int x, y;
  if (r < 130)      { y = 0;   x = r; }
  else if (r < 260) { y = 129; x = r - 130; }
  else if (r < 388) { x = 0;   y = r - 259; }
  else              { x = 129; y = r - 387; }
  u16* dst = p + (((long)b * 130 + y) * 130 + x) * 256 + c8;
  *reinterpret_cast<uint4*>(dst) = uint4{0, 0, 0, 0};
}

// ---------------- x f32 -> bf16 ----------------
__global__ void cvt_f32_bf16(const float* __restrict__ in, u16* __restrict__ out, int n4) {
  int i = blockIdx.x * blockDim.x + threadIdx.x;
  if (i >= n4) return;
  float4 v = reinterpret_cast<const float4*>(in)[i];
  ushort4 o;
  o.x = f2bf(v.x); o.y = f2bf(v.y); o.z = f2bf(v.z); o.w = f2bf(v.w);
  reinterpret_cast<ushort4*>(out)[i] = o;
}

// ---------------- combined prep: weight cvts + conv-weight packs + vpad halo ----------------
__global__ void prep(const float* __restrict__ Wq, const float* __restrict__ Wk,
                     const float* __restrict__ Wv, const float* __restrict__ Wc1,
                     const float* __restrict__ Wc2, u16* __restrict__ wqkv,
                     u16* __restrict__ wc1r, u16* __restrict__ wc2r, u16* __restrict__ vpad) {
  const int blk = blockIdx.x, t = threadIdx.x;
  if (blk < 192) {  // Wq|Wk|Wv f32 -> bf16 (16384 float4 each)
    const float* src = blk < 64 ? Wq : (blk < 128 ? Wk : Wv);
    u16* dst = wqkv + (blk < 64 ? 0 : (blk < 128 ? 65536 : 131072));
    const int i = (blk & 63) * 256 + t;
    float4 v = reinterpret_cast<const float4*>(src)[i];
    ushort4 o;
    o.x = f2bf(v.x); o.y = f2bf(v.y); o.z = f2bf(v.z); o.w = f2bf(v.w);
    reinterpret_cast<ushort4*>(dst)[i] = o;
  } else if (blk < 4800) {  // Wc[oc][ic][3][3] -> Bt[oc][(ky*3+kx)*256+ic]
    const int q = blk - 192;
    const float* w = q < 2304 ? Wc1 : Wc2;
    u16* dst = q < 2304 ? wc1r : wc2r;
    const int j = (q % 2304) * 256 + t;
    const int oc = j / 2304, r = j - oc * 2304;
    dst[j] = f2bf(w[(oc * 256 + (r & 255)) * 9 + (r >> 8)]);
  } else {
    const int idx = (blk - 4800) * 256 + t;
    if (idx < 8 * 516 * 32) border_body(vpad, idx);
  }
}

// ================= 256x256 8-phase GEMM (T2+T3+T4+T5) =================
// C[M,256*NT] = A[M,K] * Bt[.,K]^T ; 512 thr = 8 waves (2Mx4N), BK=64.
// LDS 128KB dynamic: A[2][256][64] @0, B[2][256][64] @32768 (bf16 elems),
// 16B-slot XOR swizzle (slot ^= row&7) via pre-swizzled global source.
// CONV=0: linear A [M][256]. CONV=1: padded NHWC, 3x3 halo shifts, half-image/XCD swizzle.
// CONV=2: padded NHWC, no shift (plain GEMM over vpad).
// EPI: 0 = qkv-split (q,k -> out[.,512]; v -> vp padded), 1 = f32+bias linear,
//      2 = gelu(+bias) -> bf16 padded.   PERB: Bt += bimg*65536 (per-batch weights).
template <int CONV, int KTOT, int EPI, int PERB, int NT>
__global__ __launch_bounds__(512, 1) void mm8(
    const u16* __restrict__ A, const u16* __restrict__ Bt,
    const float* __restrict__ bias, void* __restrict__ out,
    u16* __restrict__ vp) {
  extern __shared__ u16 lds[];
  constexpr int NKT = KTOT / 64;
  constexpr int NITER = NKT / 2;
  const int tid = threadIdx.x;
  const int wave = tid >> 6, lane = tid & 63;
  const int wr = wave >> 2, wcid = wave & 3;
  const int lrow = lane & 15, lk = lane >> 4;
  int bid = (int)blockIdx.x;
  int tile;
  if (CONV == 1) {  // half-image (4.3MB) per XCD per round
    const int xcd = bid & 7, k = bid >> 3;
    tile = (xcd + ((k >> 5) << 3)) * 32 + (k & 31);
  } else {
    tile = (bid & 7) * 64 + (bid >> 3);
  }
  const long rowbase = (long)tile * 256;
  const int bimg = tile >> 6;
  const int y0 = (tile & 63) * 2;
  const u16* BT = PERB ? Bt + (long)bimg * 65536 : Bt;
  int colbase = 0;

  auto STAGE = [&](int kt, int isB, int half, int bufq) {
#pragma unroll
    for (int j = 0; j < 2; ++j) {
      const int idx = j * 512 + tid;
      const int rh = idx >> 3;                    // row within half (0..127)
      const int sg = (idx & 7) ^ (rh & 7);        // pre-swizzled global 16B slot
      const u16* g;
      if (isB) {
        g = BT + (long)(colbase + half * 128 + rh) * KTOT + kt * 64 + sg * 8;
      } else if (CONV == 1) {
        const int slab = kt >> 2;
        const int c0 = (kt & 3) * 64;
        const int ky = slab / 3 - 1, kx = slab - (slab / 3) * 3 - 1;
        g = A + (((long)bimg * 130 + (y0 + half) + 1 + ky) * 130 + (rh + 1 + kx)) * 256 + c0 + sg * 8;
      } else if (CONV == 2) {
        g = A + (((long)bimg * 130 + (y0 + half) + 1) * 130 + (rh + 1)) * 256 + kt * 64 + sg * 8;
      } else {
        g = A + (rowbase + half * 128 + rh) * (long)256 + kt * 64 + sg * 8;
      }
      u16* l = lds + (isB ? 32768 : 0) + bufq * 16384 + half * 8192 + (j * 512 + wave * 64) * 8;
      gload16(g, l);
    }
  };

  for (int nt = 0; nt < NT; ++nt) {
    colbase = nt * 256;
    f32x4 acc[8][4] = {};
    bf16x8 bq[4][2];

    // prologue: t0.B0, t0.B1, t0.A0, t0.A1, t1.B0, t1.B1
    STAGE(0, 1, 0, 0); STAGE(0, 1, 1, 0);
    STAGE(0, 0, 0, 0); STAGE(0, 0, 1, 0);
    STAGE(1, 1, 0, 1); STAGE(1, 1, 1, 1);
    asm volatile("s_waitcnt vmcnt(4)" ::: "memory");
    __builtin_amdgcn_s_barrier();
    __builtin_amdgcn_sched_barrier(0);

    for (int it = 0; it < NITER; ++it) {
      const int u0 = 2 * it;
#pragma unroll
      for (int ph = 0; ph < 8; ++ph) {
        constexpr int S_ISB[8]  = {0, 0, 1, 1, 0, 0, 1, 1};
        constexpr int S_HALF[8] = {0, 1, 0, 1, 0, 1, 0, 1};
        constexpr int S_BUF[8]  = {1, 1, 0, 0, 0, 0, 1, 1};
        constexpr int S_DT[8]   = {1, 1, 2, 2, 2, 2, 3, 3};
        const int cbuf = ph >> 2, quad = ph & 3;
        if (quad == 0) {  // B frags once per K-tile (8 ds_read_b128)
#pragma unroll
          for (int nf = 0; nf < 4; ++nf)
#pragma unroll
            for (int ks = 0; ks < 2; ++ks) {
              const int n = wcid * 64 + nf * 16 + lrow;
              const int slot = (ks * 4 + lk) ^ (n & 7);
              bq[nf][ks] = *reinterpret_cast<const bf16x8*>(&lds[32768 + cbuf * 16384 + n * 64 + slot * 8]);
            }
        }
        bf16x8 aq[2][2];
#pragma unroll
        for (int mf = 0; mf < 2; ++mf)
#pragma unroll
          for (int ks = 0; ks < 2; ++ks) {
            const int r = wr * 128 + quad * 32 + mf * 16 + lrow;
            const int slot = (ks * 4 + lk) ^ (r & 7);
            aq[mf][ks] = *reinterpret_cast<const bf16x8*>(&lds[cbuf * 16384 + r * 64 + slot * 8]);
          }
        int st = u0 + S_DT[ph];
        if (st > NKT - 1) st = NKT - 1;  // epilogue dummy stages keep vmcnt counts exact
        STAGE(st, S_ISB[ph], S_HALF[ph], S_BUF[ph]);
        __builtin_amdgcn_s_barrier();
        asm volatile("s_waitcnt lgkmcnt(0)" ::: "memory");
        __builtin_amdgcn_sched_barrier(0);
        __builtin_amdgcn_s_setprio(1);
#pragma unroll
        for (int mf = 0; mf < 2; ++mf)
#pragma unroll
          for (int nf = 0; nf < 4; ++nf)
#pragma unroll
            for (int ks = 0; ks < 2; ++ks)
              acc[quad * 2 + mf][nf] = __builtin_amdgcn_mfma_f32_16x16x32_bf16(
                  aq[mf][ks], bq[nf][ks], acc[quad * 2 + mf][nf], 0, 0, 0);
        __builtin_amdgcn_s_setprio(0);
        __builtin_amdgcn_sched_barrier(0);
        if (quad == 3)
          asm volatile("s_waitcnt vmcnt(4)" ::: "memory");  // counted, never 0
        __builtin_amdgcn_s_barrier();
        __builtin_amdgcn_sched_barrier(0);
      }
    }

    // -------- epilogue --------
    const int r0 = (lane >> 4) * 4;
    const int occ = lane & 15;
#pragma unroll
    for (int M = 0; M < 8; ++M) {
#pragma unroll
      for (int nf = 0; nf < 4; ++nf) {
        const int col = wcid * 64 + nf * 16 + occ;
#pragma unroll
        for (int i = 0; i < 4; ++i) {
          const int p = wr * 128 + M * 16 + r0 + i;  // local row 0..255
          float v = acc[M][nf][i];
          if (EPI == 0) {
            const long rowpix = rowbase + p;
            const int gcol = colbase + col;
            if (gcol < 512) {
              reinterpret_cast<u16*>(out)[rowpix * 512 + gcol] = f2bf(v);
            } else {
              const int b = (int)(rowpix >> 14), rem = (int)(rowpix & 16383);
              vp[(((long)b * 130 + (rem >> 7) + 1) * 130 + (rem & 127) + 1) * 256 + (gcol - 512)] = f2bf(v);
            }
          } else if (EPI == 1) {
            reinterpret_cast<float*>(out)[(rowbase + p) * 256 + col] = v + bias[col];
          } else {
            v += bias[col];
            v = 0.5f * v * (1.0f + erff(v * 0.70710678118654752f));
            const int y = y0 + (p >> 7), x = p & 127;
            reinterpret_cast<u16*>(out)[(((long)bimg * 130 + y + 1) * 130 + x + 1) * 256 + col] = f2bf(v);
          }
        }
      }
    }
  }
}

// ---------------- G[b,h,d,e] = sum_n k[n,256+h*32+d] * q[n,h*32+e]  (+ col sumsq) ----------------
__global__ __launch_bounds__(256) void gram_kernel(const u16* __restrict__ qkv,
                                                   float* __restrict__ G,
                                                   float* __restrict__ norm2) {
  const int chunk = blockIdx.x;
  const int bh = blockIdx.y;
  const int b = bh >> 3, h = bh & 7;
  __shared__ float kk[32][33];
  __shared__ float qq[32][33];
  const int tid = threadIdx.x;
  const int rr = tid >> 3;
  const int c4 = (tid & 7) * 4;
  const long rowstart = (long)b * 16384 + (long)chunk * 2048;
  const u16* qp = qkv + rowstart * 512 + h * 32;
  const u16* kp = qp + 256;
  float acc0 = 0, acc1 = 0, acc2 = 0, acc3 = 0;
  float skk[4] = {0, 0, 0, 0}, sqq[4] = {0, 0, 0, 0};
  for (int t0 = 0; t0 < 2048; t0 += 32) {
    __syncthreads();
    ushort4 kv = *reinterpret_cast<const ushort4*>(kp + (long)(t0 + rr) * 512 + c4);
    ushort4 qv = *reinterpret_cast<const ushort4*>(qp + (long)(t0 + rr) * 512 + c4);
    float f;
    f = bf2f(kv.x); kk[rr][c4 + 0] = f; skk[0] += f * f;
    f = bf2f(kv.y); kk[rr][c4 + 1] = f; skk[1] += f * f;
    f = bf2f(kv.z); kk[rr][c4 + 2] = f; skk[2] += f * f;
    f = bf2f(kv.w); kk[rr][c4 + 3] = f; skk[3] += f * f;
    f = bf2f(qv.x); qq[rr][c4 + 0] = f; sqq[0] += f * f;
    f = bf2f(qv.y); qq[rr][c4 + 1] = f; sqq[1] += f * f;
    f = bf2f(qv.z); qq[rr][c4 + 2] = f; sqq[2] += f * f;
    f = bf2f(qv.w); qq[rr][c4 + 3] = f; sqq[3] += f * f;
    __syncthreads();
#pragma unroll
    for (int r = 0; r < 32; ++r) {
      const float kval = kk[r][rr];
      acc0 += kval * qq[r][c4 + 0];
      acc1 += kval * qq[r][c4 + 1];
      acc2 += kval * qq[r][c4 + 2];
      acc3 += kval * qq[r][c4 + 3];
    }
  }
  float* gp = G + ((long)bh * 32 + rr) * 32 + c4;
  atomicAdd(gp + 0, acc0); atomicAdd(gp + 1, acc1);
  atomicAdd(gp + 2, acc2); atomicAdd(gp + 3, acc3);
  // column sum-of-squares reduction (reuse LDS)
  __syncthreads();
  kk[rr][c4 + 0] = skk[0]; kk[rr][c4 + 1] = skk[1];
  kk[rr][c4 + 2] = skk[2]; kk[rr][c4 + 3] = skk[3];
  qq[rr][c4 + 0] = sqq[0]; qq[rr][c4 + 1] = sqq[1];
  qq[rr][c4 + 2] = sqq[2]; qq[rr][c4 + 3] = sqq[3];
  __syncthreads();
  if (tid < 64) {
    const int col = tid & 31;
    float s = 0.f;
    if (tid < 32) {
#pragma unroll
      for (int r2 = 0; r2 < 32; ++r2) s += kk[r2][col];
      atomicAdd(&norm2[b * 512 + 256 + h * 32 + col], s);
    } else {
#pragma unroll
      for (int r2 = 0; r2 < 32; ++r2) s += qq[r2][col];
      atomicAdd(&norm2[b * 512 + h * 32 + col], s);
    }
  }
}

// ---------------- normalize + rescale + softmax over e ----------------
__global__ void attn_softmax(const float* __restrict__ G, const float* __restrict__ norm2,
                             const float* __restrict__ rescale, float* __restrict__ attn) {
  const int bh = blockIdx.x;
  const int b = bh >> 3, h = bh & 7;
  const int t = threadIdx.x;
  __shared__ float iqs[32], iks[32];
  if (t < 32) {
    iqs[t] = 1.0f / fmaxf(sqrtf(norm2[b * 512 + h * 32 + t]), 1e-12f);
    iks[t] = 1.0f / fmaxf(sqrtf(norm2[b * 512 + 256 + h * 32 + t]), 1e-12f);
  }
  __syncthreads();
  if (t < 32) {
    const float rs = rescale[h];
    const float ikd = iks[t] * rs;
    const float* gp = G + ((long)bh * 32 + t) * 32;
    float l[32];
    float mx = -1e30f;
#pragma unroll
    for (int e = 0; e < 32; ++e) {
      l[e] = gp[e] * ikd * iqs[e];
      mx = fmaxf(mx, l[e]);
    }
    float s = 0.f;
#pragma unroll
    for (int e = 0; e < 32; ++e) {
      l[e] = expf(l[e] - mx);
      s += l[e];
    }
    const float inv = 1.0f / s;
    float* op = attn + ((long)bh * 32 + t) * 32;
#pragma unroll
    for (int e = 0; e < 32; ++e) op[e] = l[e] * inv;
  }
}

// ---------------- weff[b][c][h*32+e] = sum_d Wp[c][h*32+d]*attn[b][h][d][e]; + p1pad halo ----------------
__global__ __launch_bounds__(256) void weff_border(const float* __restrict__ Wp,
                                                   const float* __restrict__ attn,
                                                   u16* __restrict__ weff,
                                                   u16* __restrict__ p1pad) {
  const int blk = blockIdx.x;
  const int t = threadIdx.x;
  if (blk < 64) {
    __shared__ float A[32][33];
    const int b = blk >> 3, h = blk & 7;
    const float* ap = attn + (long)blk * 1024;
    for (int j = t; j < 1024; j += 256) A[j >> 5][j & 31] = ap[j];
    __syncthreads();
    const float* wrow = Wp + (long)t * 256 + h * 32;
    float w[32];
#pragma unroll
    for (int d = 0; d < 32; ++d) w[d] = wrow[d];
    u16* orow = weff + ((long)b * 256 + t) * 256 + h * 32;
#pragma unroll
    for (int e = 0; e < 32; ++e) {
      float s = 0.f;
#pragma unroll
      for (int d = 0; d < 32; ++d) s += w[d] * A[d][e];
      orow[e] = f2bf(s);
    }
  } else {
    const int idx = (blk - 64) * 256 + t;
    if (idx < 8 * 516 * 32) border_body(p1pad, idx);
  }
}

// ---------------- launch ----------------
extern "C" void kernel_launch(void* const* d_in, const int* in_sizes, int n_in,
                              void* d_out, int out_size, void* d_ws, size_t ws_size,
                              hipStream_t stream) {
  const float* x = (const float*)d_in[0];
  const float* Wq = (const float*)d_in[1];
  const float* Wk = (const float*)d_in[2];
  const float* Wv = (const float*)d_in[3];
  const float* resc = (const float*)d_in[4];
  const float* Wp = (const float*)d_in[5];
  const float* bp = (const float*)d_in[6];
  const float* Wc1 = (const float*)d_in[7];
  const float* bc1 = (const float*)d_in[8];
  const float* Wc2 = (const float*)d_in[9];
  const float* bc2 = (const float*)d_in[10];

  char* ws = (char*)d_ws;
  u16* qkv   = (u16*)(ws + 0L);            // [131072][512] q|k ; dead after gram
  u16* p1pad = (u16*)(ws + 0L);            // [8][130][130][256] conv1 out (overlays qkv)
  u16* vpad  = (u16*)(ws + 134217728L);    // [8][130][130][256] v padded
  u16* xb    = (u16*)(ws + 203440128L);    // x bf16
  u16* wqkv  = (u16*)(ws + 270548992L);    // [768][256]
  u16* wc1r  = (u16*)(ws + 270942208L);    // [256][2304]
  u16* wc2r  = (u16*)(ws + 272121856L);    // [256][2304]
  u16* weff  = (u16*)(ws + 273301504L);    // [8][256][256]
  float* norm2 = (float*)(ws + 274350080L);  // [8][512]
  float* G     = (float*)(ws + 274366464L);  // [64][32][32]
  float* attn  = (float*)(ws + 274628608L);  // [64][32][32]

  float* out_c = (float*)d_out;
  float* out_p = out_c + 33554432L;

  hipMemsetAsync(norm2, 0, 16384 + 262144, stream);

  cvt_f32_bf16<<<32768, 256, 0, stream>>>(x, xb, 8388608);
  prep<<<5316, 256, 0, stream>>>(Wq, Wk, Wv, Wc1, Wc2, wqkv, wc1r, wc2r, vpad);

  // QKV projection: q,k -> qkv[131072][512]; v -> vpad  (3 col-tiles looped in-block)
  mm8<0, 256, 0, 0, 3><<<512, 512, 131072, stream>>>(xb, wqkv, nullptr, qkv, vpad);

  gram_kernel<<<dim3(8, 64), 256, 0, stream>>>(qkv, G, norm2);
  attn_softmax<<<64, 64, 0, stream>>>(G, norm2, resc, attn);
  weff_border<<<580, 256, 0, stream>>>(Wp, attn, weff, p1pad);

  // out_c = v @ weff[b]^T + bp   (reads vpad directly; xo_apply eliminated)
  mm8<2, 256, 1, 1, 1><<<512, 512, 131072, stream>>>(vpad, weff, bp, out_c, nullptr);

  // conv branch
  mm8<1, 2304, 2, 0, 1><<<512, 512, 131072, stream>>>(vpad, wc1r, bc1, p1pad, nullptr);
  mm8<1, 2304, 1, 0, 1><<<512, 512, 131072, stream>>>(p1pad, wc2r, bc2, out_p, nullptr);
}

// Round 5
// 630.365 us; speedup vs baseline: 1.4184x; 1.1637x over previous
//
#include <hip/hip_runtime.h>
#include <cstdint>

#define DEV __device__ __forceinline__

typedef __bf16 bf16x8 __attribute__((ext_vector_type(8)));
typedef float f32x4 __attribute__((ext_vector_type(4)));
typedef unsigned int u32;
typedef unsigned short u16;

DEV u16 f2bf(float f) {
  u32 u = __builtin_bit_cast(u32, f);
  u += 0x7fffu + ((u >> 16) & 1u);
  return (u16)(u >> 16);
}
DEV float bf2f(u16 b) { return __builtin_bit_cast(float, (u32)b << 16); }

// global -> LDS direct DMA, 16B per lane. LDS dest wave-uniform; HW adds lane*16.
DEV void gload16(const u16* g, u16* l) {
  __builtin_amdgcn_global_load_lds(
      (const __attribute__((address_space(1))) u32*)g,
      (__attribute__((address_space(3))) u32*)(uintptr_t)l, 16, 0, 0);
}

// zero the 1-pixel halo of a [8][130][130][256] bf16 buffer; idx < 8*516*32
DEV void border_body(u16* __restrict__ p, int idx) {
  int pix = idx >> 5, c8 = (idx & 31) << 3;
  int b = pix / 516, r = pix % 516;
  int x, y;
  if (r < 130)      { y = 0;   x = r; }
  else if (r < 260) { y = 129; x = r - 130; }
  else if (r < 388) { x = 0;   y = r - 259; }
  else              { x = 129; y = r - 387; }
  u16* dst = p + (((long)b * 130 + y) * 130 + x) * 256 + c8;
  *reinterpret_cast<uint4*>(dst) = uint4{0, 0, 0, 0};
}

// ---------------- x f32 -> bf16 ----------------
__global__ void cvt_f32_bf16(const float* __restrict__ in, u16* __restrict__ out, int n4) {
  int i = blockIdx.x * blockDim.x + threadIdx.x;
  if (i >= n4) return;
  float4 v = reinterpret_cast<const float4*>(in)[i];
  ushort4 o;
  o.x = f2bf(v.x); o.y = f2bf(v.y); o.z = f2bf(v.z); o.w = f2bf(v.w);
  reinterpret_cast<ushort4*>(out)[i] = o;
}

// ---------------- combined prep: weight cvts + conv-weight packs + vpad halo ----------------
__global__ void prep(const float* __restrict__ Wq, const float* __restrict__ Wk,
                     const float* __restrict__ Wv, const float* __restrict__ Wc1,
                     const float* __restrict__ Wc2, u16* __restrict__ wqkv,
                     u16* __restrict__ wc1r, u16* __restrict__ wc2r, u16* __restrict__ vpad) {
  const int blk = blockIdx.x, t = threadIdx.x;
  if (blk < 192) {  // Wq|Wk|Wv f32 -> bf16 (16384 float4 each)
    const float* src = blk < 64 ? Wq : (blk < 128 ? Wk : Wv);
    u16* dst = wqkv + (blk < 64 ? 0 : (blk < 128 ? 65536 : 131072));
    const int i = (blk & 63) * 256 + t;
    float4 v = reinterpret_cast<const float4*>(src)[i];
    ushort4 o;
    o.x = f2bf(v.x); o.y = f2bf(v.y); o.z = f2bf(v.z); o.w = f2bf(v.w);
    reinterpret_cast<ushort4*>(dst)[i] = o;
  } else if (blk < 4800) {  // Wc[oc][ic][3][3] -> Bt[oc][(ky*3+kx)*256+ic]
    const int q = blk - 192;
    const float* w = q < 2304 ? Wc1 : Wc2;
    u16* dst = q < 2304 ? wc1r : wc2r;
    const int j = (q % 2304) * 256 + t;
    const int oc = j / 2304, r = j - oc * 2304;
    dst[j] = f2bf(w[(oc * 256 + (r & 255)) * 9 + (r >> 8)]);
  } else {
    const int idx = (blk - 4800) * 256 + t;
    if (idx < 8 * 516 * 32) border_body(vpad, idx);
  }
}

// ================= 256x256 8-phase GEMM (T2+T3+T4+T5) =================
// C tile = A[M,K] * Bt[.,K]^T ; 512 thr = 8 waves (2Mx4N), BK=64.
// LDS 128KB dynamic: A[2][256][64] @0, B[2][256][64] @32768 (bf16 elems),
// 16B-slot XOR swizzle (slot ^= row&7) via pre-swizzled global source.
// CONV=0: linear A [M][256]. CONV=1: padded NHWC, 3x3 halo shifts.
// CONV=2: padded NHWC, no shift (plain GEMM over vpad).
// SWZ=0: 512-block XCD round-robin. SWZ=1: conv half-image per XCD.
// SWZ=2: QKV 1536-block: 3 col-tiles of each row-tile co-resident on one XCD
//        (A-tile fetched once from HBM, L2-hit for the other two).
// EPI: 0 = qkv-split (q,k -> out[.,512]; v -> vp padded), 1 = f32+bias linear,
//      2 = gelu(+bias) -> bf16 padded.   PERB: Bt += bimg*65536 (per-batch weights).
template <int CONV, int KTOT, int EPI, int PERB, int SWZ>
__global__ __launch_bounds__(512, 1) void mm8(
    const u16* __restrict__ A, const u16* __restrict__ Bt,
    const float* __restrict__ bias, void* __restrict__ out,
    u16* __restrict__ vp) {
  extern __shared__ u16 lds[];
  constexpr int NKT = KTOT / 64;
  constexpr int NITER = NKT / 2;
  const int tid = threadIdx.x;
  const int wave = tid >> 6, lane = tid & 63;
  const int wr = wave >> 2, wcid = wave & 3;
  const int lrow = lane & 15, lk = lane >> 4;
  int bid = (int)blockIdx.x;
  int tile, colbase;
  if (SWZ == 1) {  // half-image (4.3MB) per XCD per round
    const int xcd = bid & 7, k = bid >> 3;
    tile = (xcd + ((k >> 5) << 3)) * 32 + (k & 31);
    colbase = 0;
  } else if (SWZ == 2) {  // qkv: row-tile's 3 col-tiles adjacent on same XCD
    const int xcd = bid & 7, s = bid >> 3;
    const int r = s / 3;
    tile = xcd * 64 + r;
    colbase = (s - r * 3) * 256;
  } else {
    tile = (bid & 7) * 64 + (bid >> 3);
    colbase = 0;
  }
  const long rowbase = (long)tile * 256;
  const int bimg = tile >> 6;
  const int y0 = (tile & 63) * 2;
  const u16* BT = PERB ? Bt + (long)bimg * 65536 : Bt;

  auto STAGE = [&](int kt, int isB, int half, int bufq) {
#pragma unroll
    for (int j = 0; j < 2; ++j) {
      const int idx = j * 512 + tid;
      const int rh = idx >> 3;                    // row within half (0..127)
      const int sg = (idx & 7) ^ (rh & 7);        // pre-swizzled global 16B slot
      const u16* g;
      if (isB) {
        g = BT + (long)(colbase + half * 128 + rh) * KTOT + kt * 64 + sg * 8;
      } else if (CONV == 1) {
        const int slab = kt >> 2;
        const int c0 = (kt & 3) * 64;
        const int ky = slab / 3 - 1, kx = slab - (slab / 3) * 3 - 1;
        g = A + (((long)bimg * 130 + (y0 + half) + 1 + ky) * 130 + (rh + 1 + kx)) * 256 + c0 + sg * 8;
      } else if (CONV == 2) {
        g = A + (((long)bimg * 130 + (y0 + half) + 1) * 130 + (rh + 1)) * 256 + kt * 64 + sg * 8;
      } else {
        g = A + (rowbase + half * 128 + rh) * (long)256 + kt * 64 + sg * 8;
      }
      u16* l = lds + (isB ? 32768 : 0) + bufq * 16384 + half * 8192 + (j * 512 + wave * 64) * 8;
      gload16(g, l);
    }
  };

  f32x4 acc[8][4] = {};
  bf16x8 bq[4][2];

  // prologue: t0.B0, t0.B1, t0.A0, t0.A1, t1.B0, t1.B1
  STAGE(0, 1, 0, 0); STAGE(0, 1, 1, 0);
  STAGE(0, 0, 0, 0); STAGE(0, 0, 1, 0);
  STAGE(1, 1, 0, 1); STAGE(1, 1, 1, 1);
  asm volatile("s_waitcnt vmcnt(4)" ::: "memory");
  __builtin_amdgcn_s_barrier();
  __builtin_amdgcn_sched_barrier(0);

  for (int it = 0; it < NITER; ++it) {
    const int u0 = 2 * it;
#pragma unroll
    for (int ph = 0; ph < 8; ++ph) {
      constexpr int S_ISB[8]  = {0, 0, 1, 1, 0, 0, 1, 1};
      constexpr int S_HALF[8] = {0, 1, 0, 1, 0, 1, 0, 1};
      constexpr int S_BUF[8]  = {1, 1, 0, 0, 0, 0, 1, 1};
      constexpr int S_DT[8]   = {1, 1, 2, 2, 2, 2, 3, 3};
      const int cbuf = ph >> 2, quad = ph & 3;
      if (quad == 0) {  // B frags once per K-tile (8 ds_read_b128)
#pragma unroll
        for (int nf = 0; nf < 4; ++nf)
#pragma unroll
          for (int ks = 0; ks < 2; ++ks) {
            const int n = wcid * 64 + nf * 16 + lrow;
            const int slot = (ks * 4 + lk) ^ (n & 7);
            bq[nf][ks] = *reinterpret_cast<const bf16x8*>(&lds[32768 + cbuf * 16384 + n * 64 + slot * 8]);
          }
      }
      bf16x8 aq[2][2];
#pragma unroll
      for (int mf = 0; mf < 2; ++mf)
#pragma unroll
        for (int ks = 0; ks < 2; ++ks) {
          const int r = wr * 128 + quad * 32 + mf * 16 + lrow;
          const int slot = (ks * 4 + lk) ^ (r & 7);
          aq[mf][ks] = *reinterpret_cast<const bf16x8*>(&lds[cbuf * 16384 + r * 64 + slot * 8]);
        }
      int st = u0 + S_DT[ph];
      if (st > NKT - 1) st = NKT - 1;  // epilogue dummy stages keep vmcnt counts exact
      STAGE(st, S_ISB[ph], S_HALF[ph], S_BUF[ph]);
      __builtin_amdgcn_s_barrier();
      asm volatile("s_waitcnt lgkmcnt(0)" ::: "memory");
      __builtin_amdgcn_sched_barrier(0);
      __builtin_amdgcn_s_setprio(1);
#pragma unroll
      for (int mf = 0; mf < 2; ++mf)
#pragma unroll
        for (int nf = 0; nf < 4; ++nf)
#pragma unroll
          for (int ks = 0; ks < 2; ++ks)
            acc[quad * 2 + mf][nf] = __builtin_amdgcn_mfma_f32_16x16x32_bf16(
                aq[mf][ks], bq[nf][ks], acc[quad * 2 + mf][nf], 0, 0, 0);
      __builtin_amdgcn_s_setprio(0);
      __builtin_amdgcn_sched_barrier(0);
      if (quad == 3)
        asm volatile("s_waitcnt vmcnt(4)" ::: "memory");  // counted, never 0
      __builtin_amdgcn_s_barrier();
      __builtin_amdgcn_sched_barrier(0);
    }
  }

  // -------- epilogue --------
  const int r0 = (lane >> 4) * 4;
  const int occ = lane & 15;
#pragma unroll
  for (int M = 0; M < 8; ++M) {
#pragma unroll
    for (int nf = 0; nf < 4; ++nf) {
      const int col = wcid * 64 + nf * 16 + occ;
#pragma unroll
      for (int i = 0; i < 4; ++i) {
        const int p = wr * 128 + M * 16 + r0 + i;  // local row 0..255
        float v = acc[M][nf][i];
        if (EPI == 0) {
          const long rowpix = rowbase + p;
          const int gcol = colbase + col;
          if (gcol < 512) {
            reinterpret_cast<u16*>(out)[rowpix * 512 + gcol] = f2bf(v);
          } else {
            const int b = (int)(rowpix >> 14), rem = (int)(rowpix & 16383);
            vp[(((long)b * 130 + (rem >> 7) + 1) * 130 + (rem & 127) + 1) * 256 + (gcol - 512)] = f2bf(v);
          }
        } else if (EPI == 1) {
          reinterpret_cast<float*>(out)[(rowbase + p) * 256 + col] = v + bias[col];
        } else {
          v += bias[col];
          v = 0.5f * v * (1.0f + erff(v * 0.70710678118654752f));
          const int y = y0 + (p >> 7), x = p & 127;
          reinterpret_cast<u16*>(out)[(((long)bimg * 130 + y + 1) * 130 + x + 1) * 256 + col] = f2bf(v);
        }
      }
    }
  }
}

// ---------------- G[b,h,d,e] = sum_n k[n,256+h*32+d] * q[n,h*32+e]  (+ col sumsq) ----------------
__global__ __launch_bounds__(256) void gram_kernel(const u16* __restrict__ qkv,
                                                   float* __restrict__ G,
                                                   float* __restrict__ norm2) {
  const int chunk = blockIdx.x;
  const int bh = blockIdx.y;
  const int b = bh >> 3, h = bh & 7;
  __shared__ float kk[32][33];
  __shared__ float qq[32][33];
  const int tid = threadIdx.x;
  const int rr = tid >> 3;
  const int c4 = (tid & 7) * 4;
  const long rowstart = (long)b * 16384 + (long)chunk * 2048;
  const u16* qp = qkv + rowstart * 512 + h * 32;
  const u16* kp = qp + 256;
  float acc0 = 0, acc1 = 0, acc2 = 0, acc3 = 0;
  float skk[4] = {0, 0, 0, 0}, sqq[4] = {0, 0, 0, 0};
  for (int t0 = 0; t0 < 2048; t0 += 32) {
    __syncthreads();
    ushort4 kv = *reinterpret_cast<const ushort4*>(kp + (long)(t0 + rr) * 512 + c4);
    ushort4 qv = *reinterpret_cast<const ushort4*>(qp + (long)(t0 + rr) * 512 + c4);
    float f;
    f = bf2f(kv.x); kk[rr][c4 + 0] = f; skk[0] += f * f;
    f = bf2f(kv.y); kk[rr][c4 + 1] = f; skk[1] += f * f;
    f = bf2f(kv.z); kk[rr][c4 + 2] = f; skk[2] += f * f;
    f = bf2f(kv.w); kk[rr][c4 + 3] = f; skk[3] += f * f;
    f = bf2f(qv.x); qq[rr][c4 + 0] = f; sqq[0] += f * f;
    f = bf2f(qv.y); qq[rr][c4 + 1] = f; sqq[1] += f * f;
    f = bf2f(qv.z); qq[rr][c4 + 2] = f; sqq[2] += f * f;
    f = bf2f(qv.w); qq[rr][c4 + 3] = f; sqq[3] += f * f;
    __syncthreads();
#pragma unroll
    for (int r = 0; r < 32; ++r) {
      const float kval = kk[r][rr];
      acc0 += kval * qq[r][c4 + 0];
      acc1 += kval * qq[r][c4 + 1];
      acc2 += kval * qq[r][c4 + 2];
      acc3 += kval * qq[r][c4 + 3];
    }
  }
  float* gp = G + ((long)bh * 32 + rr) * 32 + c4;
  atomicAdd(gp + 0, acc0); atomicAdd(gp + 1, acc1);
  atomicAdd(gp + 2, acc2); atomicAdd(gp + 3, acc3);
  // column sum-of-squares reduction (reuse LDS)
  __syncthreads();
  kk[rr][c4 + 0] = skk[0]; kk[rr][c4 + 1] = skk[1];
  kk[rr][c4 + 2] = skk[2]; kk[rr][c4 + 3] = skk[3];
  qq[rr][c4 + 0] = sqq[0]; qq[rr][c4 + 1] = sqq[1];
  qq[rr][c4 + 2] = sqq[2]; qq[rr][c4 + 3] = sqq[3];
  __syncthreads();
  if (tid < 64) {
    const int col = tid & 31;
    float s = 0.f;
    if (tid < 32) {
#pragma unroll
      for (int r2 = 0; r2 < 32; ++r2) s += kk[r2][col];
      atomicAdd(&norm2[b * 512 + 256 + h * 32 + col], s);
    } else {
#pragma unroll
      for (int r2 = 0; r2 < 32; ++r2) s += qq[r2][col];
      atomicAdd(&norm2[b * 512 + h * 32 + col], s);
    }
  }
}

// ---------------- normalize + rescale + softmax over e ----------------
__global__ void attn_softmax(const float* __restrict__ G, const float* __restrict__ norm2,
                             const float* __restrict__ rescale, float* __restrict__ attn) {
  const int bh = blockIdx.x;
  const int b = bh >> 3, h = bh & 7;
  const int t = threadIdx.x;
  __shared__ float iqs[32], iks[32];
  if (t < 32) {
    iqs[t] = 1.0f / fmaxf(sqrtf(norm2[b * 512 + h * 32 + t]), 1e-12f);
    iks[t] = 1.0f / fmaxf(sqrtf(norm2[b * 512 + 256 + h * 32 + t]), 1e-12f);
  }
  __syncthreads();
  if (t < 32) {
    const float rs = rescale[h];
    const float ikd = iks[t] * rs;
    const float* gp = G + ((long)bh * 32 + t) * 32;
    float l[32];
    float mx = -1e30f;
#pragma unroll
    for (int e = 0; e < 32; ++e) {
      l[e] = gp[e] * ikd * iqs[e];
      mx = fmaxf(mx, l[e]);
    }
    float s = 0.f;
#pragma unroll
    for (int e = 0; e < 32; ++e) {
      l[e] = expf(l[e] - mx);
      s += l[e];
    }
    const float inv = 1.0f / s;
    float* op = attn + ((long)bh * 32 + t) * 32;
#pragma unroll
    for (int e = 0; e < 32; ++e) op[e] = l[e] * inv;
  }
}

// ---------------- weff[b][c][h*32+e] = sum_d Wp[c][h*32+d]*attn[b][h][d][e]; + p1pad halo ----------------
__global__ __launch_bounds__(256) void weff_border(const float* __restrict__ Wp,
                                                   const float* __restrict__ attn,
                                                   u16* __restrict__ weff,
                                                   u16* __restrict__ p1pad) {
  const int blk = blockIdx.x;
  const int t = threadIdx.x;
  if (blk < 64) {
    __shared__ float A[32][33];
    const int b = blk >> 3, h = blk & 7;
    const float* ap = attn + (long)blk * 1024;
    for (int j = t; j < 1024; j += 256) A[j >> 5][j & 31] = ap[j];
    __syncthreads();
    const float* wrow = Wp + (long)t * 256 + h * 32;
    float w[32];
#pragma unroll
    for (int d = 0; d < 32; ++d) w[d] = wrow[d];
    u16* orow = weff + ((long)b * 256 + t) * 256 + h * 32;
#pragma unroll
    for (int e = 0; e < 32; ++e) {
      float s = 0.f;
#pragma unroll
      for (int d = 0; d < 32; ++d) s += w[d] * A[d][e];
      orow[e] = f2bf(s);
    }
  } else {
    const int idx = (blk - 64) * 256 + t;
    if (idx < 8 * 516 * 32) border_body(p1pad, idx);
  }
}

// ---------------- launch ----------------
extern "C" void kernel_launch(void* const* d_in, const int* in_sizes, int n_in,
                              void* d_out, int out_size, void* d_ws, size_t ws_size,
                              hipStream_t stream) {
  const float* x = (const float*)d_in[0];
  const float* Wq = (const float*)d_in[1];
  const float* Wk = (const float*)d_in[2];
  const float* Wv = (const float*)d_in[3];
  const float* resc = (const float*)d_in[4];
  const float* Wp = (const float*)d_in[5];
  const float* bp = (const float*)d_in[6];
  const float* Wc1 = (const float*)d_in[7];
  const float* bc1 = (const float*)d_in[8];
  const float* Wc2 = (const float*)d_in[9];
  const float* bc2 = (const float*)d_in[10];

  char* ws = (char*)d_ws;
  u16* qkv   = (u16*)(ws + 0L);            // [131072][512] q|k ; dead after gram
  u16* p1pad = (u16*)(ws + 0L);            // [8][130][130][256] conv1 out (overlays qkv)
  u16* vpad  = (u16*)(ws + 134217728L);    // [8][130][130][256] v padded
  u16* xb    = (u16*)(ws + 203440128L);    // x bf16
  u16* wqkv  = (u16*)(ws + 270548992L);    // [768][256]
  u16* wc1r  = (u16*)(ws + 270942208L);    // [256][2304]
  u16* wc2r  = (u16*)(ws + 272121856L);    // [256][2304]
  u16* weff  = (u16*)(ws + 273301504L);    // [8][256][256]
  float* norm2 = (float*)(ws + 274350080L);  // [8][512]
  float* G     = (float*)(ws + 274366464L);  // [64][32][32]
  float* attn  = (float*)(ws + 274628608L);  // [64][32][32]

  float* out_c = (float*)d_out;
  float* out_p = out_c + 33554432L;

  hipMemsetAsync(norm2, 0, 16384 + 262144, stream);

  cvt_f32_bf16<<<32768, 256, 0, stream>>>(x, xb, 8388608);
  prep<<<5316, 256, 0, stream>>>(Wq, Wk, Wv, Wc1, Wc2, wqkv, wc1r, wc2r, vpad);

  // QKV projection: q,k -> qkv[131072][512]; v -> vpad (1536 blocks, co-XCD col-tiles)
  mm8<0, 256, 0, 0, 2><<<1536, 512, 131072, stream>>>(xb, wqkv, nullptr, qkv, vpad);

  gram_kernel<<<dim3(8, 64), 256, 0, stream>>>(qkv, G, norm2);
  attn_softmax<<<64, 64, 0, stream>>>(G, norm2, resc, attn);
  weff_border<<<580, 256, 0, stream>>>(Wp, attn, weff, p1pad);

  // out_c = v @ weff[b]^T + bp   (reads vpad directly)
  mm8<2, 256, 1, 1, 0><<<512, 512, 131072, stream>>>(vpad, weff, bp, out_c, nullptr);

  // conv branch
  mm8<1, 2304, 2, 0, 1><<<512, 512, 131072, stream>>>(vpad, wc1r, bc1, p1pad, nullptr);
  mm8<1, 2304, 1, 0, 1><<<512, 512, 131072, stream>>>(p1pad, wc2r, bc2, out_p, nullptr);
}

// Round 6
// 625.129 us; speedup vs baseline: 1.4302x; 1.0084x over previous
//
#include <hip/hip_runtime.h>
#include <cstdint>

#define DEV __device__ __forceinline__

typedef __bf16 bf16x8 __attribute__((ext_vector_type(8)));
typedef float f32x4 __attribute__((ext_vector_type(4)));
typedef unsigned int u32;
typedef unsigned short u16;

DEV u16 f2bf(float f) {
  u32 u = __builtin_bit_cast(u32, f);
  u += 0x7fffu + ((u >> 16) & 1u);
  return (u16)(u >> 16);
}
DEV float bf2f(u16 b) { return __builtin_bit_cast(float, (u32)b << 16); }

// global -> LDS direct DMA, 16B per lane. LDS dest wave-uniform; HW adds lane*16.
DEV void gload16(const u16* g, u16* l) {
  __builtin_amdgcn_global_load_lds(
      (const __attribute__((address_space(1))) u32*)g,
      (__attribute__((address_space(3))) u32*)(uintptr_t)l, 16, 0, 0);
}

// zero the 1-pixel halo of a [8][130][130][256] bf16 buffer; idx < 8*516*32
DEV void border_body(u16* __restrict__ p, int idx) {
  int pix = idx >> 5, c8 = (idx & 31) << 3;
  int b = pix / 516, r = pix % 516;
  int x, y;
  if (r < 130)      { y = 0;   x = r; }
  else if (r < 260) { y = 129; x = r - 130; }
  else if (r < 388) { x = 0;   y = r - 259; }
  else              { x = 129; y = r - 387; }
  u16* dst = p + (((long)b * 130 + y) * 130 + x) * 256 + c8;
  *reinterpret_cast<uint4*>(dst) = uint4{0, 0, 0, 0};
}

// ---------------- x f32 -> bf16 ----------------
__global__ void cvt_f32_bf16(const float* __restrict__ in, u16* __restrict__ out, int n4) {
  int i = blockIdx.x * blockDim.x + threadIdx.x;
  if (i >= n4) return;
  float4 v = reinterpret_cast<const float4*>(in)[i];
  ushort4 o;
  o.x = f2bf(v.x); o.y = f2bf(v.y); o.z = f2bf(v.z); o.w = f2bf(v.w);
  reinterpret_cast<ushort4*>(out)[i] = o;
}

// ---------------- combined prep: weight cvts + conv-weight packs + vpad halo ----------------
// Conv-B layout (cgroup-outer K-order): column r = kt*64 + c_lo, kt = cg*9 + slab,
// slab = ky*3+kx, ic = cg*64 + c_lo.  (L2-locality: conv K-loop cycles the 9 halo
// shifts within one 64-channel group before moving to the next group.)
__global__ void prep(const float* __restrict__ Wq, const float* __restrict__ Wk,
                     const float* __restrict__ Wv, const float* __restrict__ Wc1,
                     const float* __restrict__ Wc2, u16* __restrict__ wqkv,
                     u16* __restrict__ wc1r, u16* __restrict__ wc2r, u16* __restrict__ vpad) {
  const int blk = blockIdx.x, t = threadIdx.x;
  if (blk < 192) {  // Wq|Wk|Wv f32 -> bf16 (16384 float4 each)
    const float* src = blk < 64 ? Wq : (blk < 128 ? Wk : Wv);
    u16* dst = wqkv + (blk < 64 ? 0 : (blk < 128 ? 65536 : 131072));
    const int i = (blk & 63) * 256 + t;
    float4 v = reinterpret_cast<const float4*>(src)[i];
    ushort4 o;
    o.x = f2bf(v.x); o.y = f2bf(v.y); o.z = f2bf(v.z); o.w = f2bf(v.w);
    reinterpret_cast<ushort4*>(dst)[i] = o;
  } else if (blk < 4800) {  // Wc[oc][ic][3][3] -> Bt[oc][(cg*9+slab)*64 + c_lo]
    const int q = blk - 192;
    const float* w = q < 2304 ? Wc1 : Wc2;
    u16* dst = q < 2304 ? wc1r : wc2r;
    const int j = (q % 2304) * 256 + t;
    const int oc = j / 2304, r = j - oc * 2304;
    const int kt = r >> 6, c_lo = r & 63;
    const int cg = kt / 9, slab = kt - cg * 9;
    const int ic = cg * 64 + c_lo;
    dst[j] = f2bf(w[(oc * 256 + ic) * 9 + slab]);
  } else {
    const int idx = (blk - 4800) * 256 + t;
    if (idx < 8 * 516 * 32) border_body(vpad, idx);
  }
}

// ================= 256x256 8-phase GEMM (T2+T3+T4+T5) =================
// C tile = A[M,K] * Bt[.,K]^T ; 512 thr = 8 waves (2Mx4N), BK=64.
// LDS 128KB dynamic: A[2][256][64] @0, B[2][256][64] @32768 (bf16 elems),
// 16B-slot XOR swizzle (slot ^= row&7) via pre-swizzled global source.
// CONV=0: linear A [M][256]. CONV=1: padded NHWC, 3x3 halo shifts, K-order
//   kt = cg*9 + slab (channel-group outer) matching prep's conv-B pack.
// CONV=2: padded NHWC, no shift (plain GEMM over vpad).
// SWZ=0: 512-block XCD round-robin. SWZ=1: conv half-image per XCD.
// SWZ=2: QKV 1536-block: 3 col-tiles of each row-tile co-resident on one XCD.
// EPI: 0 = qkv-split (q,k -> out[.,512]; v -> vp padded), 1 = f32+bias linear,
//      2 = gelu(+bias) -> bf16 padded.   PERB: Bt += bimg*65536 (per-batch weights).
template <int CONV, int KTOT, int EPI, int PERB, int SWZ>
__global__ __launch_bounds__(512, 1) void mm8(
    const u16* __restrict__ A, const u16* __restrict__ Bt,
    const float* __restrict__ bias, void* __restrict__ out,
    u16* __restrict__ vp) {
  extern __shared__ u16 lds[];
  constexpr int NKT = KTOT / 64;
  constexpr int NITER = NKT / 2;
  const int tid = threadIdx.x;
  const int wave = tid >> 6, lane = tid & 63;
  const int wr = wave >> 2, wcid = wave & 3;
  const int lrow = lane & 15, lk = lane >> 4;
  int bid = (int)blockIdx.x;
  int tile, colbase;
  if (SWZ == 1) {  // half-image per XCD per round; contiguous 2-row tiles
    const int xcd = bid & 7, k = bid >> 3;
    tile = (xcd + ((k >> 5) << 3)) * 32 + (k & 31);
    colbase = 0;
  } else if (SWZ == 2) {  // qkv: row-tile's 3 col-tiles adjacent on same XCD
    const int xcd = bid & 7, s = bid >> 3;
    const int r = s / 3;
    tile = xcd * 64 + r;
    colbase = (s - r * 3) * 256;
  } else {
    tile = (bid & 7) * 64 + (bid >> 3);
    colbase = 0;
  }
  const long rowbase = (long)tile * 256;
  const int bimg = tile >> 6;
  const int y0 = (tile & 63) * 2;
  const u16* BT = PERB ? Bt + (long)bimg * 65536 : Bt;

  auto STAGE = [&](int kt, int isB, int half, int bufq) {
#pragma unroll
    for (int j = 0; j < 2; ++j) {
      const int idx = j * 512 + tid;
      const int rh = idx >> 3;                    // row within half (0..127)
      const int sg = (idx & 7) ^ (rh & 7);        // pre-swizzled global 16B slot
      const u16* g;
      if (isB) {
        g = BT + (long)(colbase + half * 128 + rh) * KTOT + kt * 64 + sg * 8;
      } else if (CONV == 1) {
        const int cg = kt / 9;                    // channel group (outer)
        const int slab = kt - cg * 9;             // halo shift (inner)
        const int ky = slab / 3 - 1, kx = slab - (slab / 3) * 3 - 1;
        const int c0 = cg * 64;
        g = A + (((long)bimg * 130 + (y0 + half) + 1 + ky) * 130 + (rh + 1 + kx)) * 256 + c0 + sg * 8;
      } else if (CONV == 2) {
        g = A + (((long)bimg * 130 + (y0 + half) + 1) * 130 + (rh + 1)) * 256 + kt * 64 + sg * 8;
      } else {
        g = A + (rowbase + half * 128 + rh) * (long)256 + kt * 64 + sg * 8;
      }
      u16* l = lds + (isB ? 32768 : 0) + bufq * 16384 + half * 8192 + (j * 512 + wave * 64) * 8;
      gload16(g, l);
    }
  };

  f32x4 acc[8][4] = {};
  bf16x8 bq[4][2];

  // prologue: t0.B0, t0.B1, t0.A0, t0.A1, t1.B0, t1.B1
  STAGE(0, 1, 0, 0); STAGE(0, 1, 1, 0);
  STAGE(0, 0, 0, 0); STAGE(0, 0, 1, 0);
  STAGE(1, 1, 0, 1); STAGE(1, 1, 1, 1);
  asm volatile("s_waitcnt vmcnt(4)" ::: "memory");
  __builtin_amdgcn_s_barrier();
  __builtin_amdgcn_sched_barrier(0);

  for (int it = 0; it < NITER; ++it) {
    const int u0 = 2 * it;
#pragma unroll
    for (int ph = 0; ph < 8; ++ph) {
      constexpr int S_ISB[8]  = {0, 0, 1, 1, 0, 0, 1, 1};
      constexpr int S_HALF[8] = {0, 1, 0, 1, 0, 1, 0, 1};
      constexpr int S_BUF[8]  = {1, 1, 0, 0, 0, 0, 1, 1};
      constexpr int S_DT[8]   = {1, 1, 2, 2, 2, 2, 3, 3};
      const int cbuf = ph >> 2, quad = ph & 3;
      if (quad == 0) {  // B frags once per K-tile (8 ds_read_b128)
#pragma unroll
        for (int nf = 0; nf < 4; ++nf)
#pragma unroll
          for (int ks = 0; ks < 2; ++ks) {
            const int n = wcid * 64 + nf * 16 + lrow;
            const int slot = (ks * 4 + lk) ^ (n & 7);
            bq[nf][ks] = *reinterpret_cast<const bf16x8*>(&lds[32768 + cbuf * 16384 + n * 64 + slot * 8]);
          }
      }
      bf16x8 aq[2][2];
#pragma unroll
      for (int mf = 0; mf < 2; ++mf)
#pragma unroll
        for (int ks = 0; ks < 2; ++ks) {
          const int r = wr * 128 + quad * 32 + mf * 16 + lrow;
          const int slot = (ks * 4 + lk) ^ (r & 7);
          aq[mf][ks] = *reinterpret_cast<const bf16x8*>(&lds[cbuf * 16384 + r * 64 + slot * 8]);
        }
      int st = u0 + S_DT[ph];
      if (st > NKT - 1) st = NKT - 1;  // epilogue dummy stages keep vmcnt counts exact
      STAGE(st, S_ISB[ph], S_HALF[ph], S_BUF[ph]);
      if (quad == 0)
        asm volatile("s_waitcnt lgkmcnt(8)" ::: "memory");  // early partial drain (12 reads issued)
      __builtin_amdgcn_s_barrier();
      asm volatile("s_waitcnt lgkmcnt(0)" ::: "memory");
      __builtin_amdgcn_sched_barrier(0);
      __builtin_amdgcn_s_setprio(1);
#pragma unroll
      for (int mf = 0; mf < 2; ++mf)
#pragma unroll
        for (int nf = 0; nf < 4; ++nf)
#pragma unroll
          for (int ks = 0; ks < 2; ++ks)
            acc[quad * 2 + mf][nf] = __builtin_amdgcn_mfma_f32_16x16x32_bf16(
                aq[mf][ks], bq[nf][ks], acc[quad * 2 + mf][nf], 0, 0, 0);
      __builtin_amdgcn_s_setprio(0);
      __builtin_amdgcn_sched_barrier(0);
      if (quad == 3)
        asm volatile("s_waitcnt vmcnt(4)" ::: "memory");  // counted, never 0
      __builtin_amdgcn_s_barrier();
      __builtin_amdgcn_sched_barrier(0);
    }
  }

  // -------- epilogue --------
  const int r0 = (lane >> 4) * 4;
  const int occ = lane & 15;
#pragma unroll
  for (int M = 0; M < 8; ++M) {
#pragma unroll
    for (int nf = 0; nf < 4; ++nf) {
      const int col = wcid * 64 + nf * 16 + occ;
#pragma unroll
      for (int i = 0; i < 4; ++i) {
        const int p = wr * 128 + M * 16 + r0 + i;  // local row 0..255
        float v = acc[M][nf][i];
        if (EPI == 0) {
          const long rowpix = rowbase + p;
          const int gcol = colbase + col;
          if (gcol < 512) {
            reinterpret_cast<u16*>(out)[rowpix * 512 + gcol] = f2bf(v);
          } else {
            const int b = (int)(rowpix >> 14), rem = (int)(rowpix & 16383);
            vp[(((long)b * 130 + (rem >> 7) + 1) * 130 + (rem & 127) + 1) * 256 + (gcol - 512)] = f2bf(v);
          }
        } else if (EPI == 1) {
          reinterpret_cast<float*>(out)[(rowbase + p) * 256 + col] = v + bias[col];
        } else {
          v += bias[col];
          v = 0.5f * v * (1.0f + erff(v * 0.70710678118654752f));
          const int y = y0 + (p >> 7), x = p & 127;
          reinterpret_cast<u16*>(out)[(((long)bimg * 130 + y + 1) * 130 + x + 1) * 256 + col] = f2bf(v);
        }
      }
    }
  }
}

// ---------------- G[b,h,d,e] = sum_n k[n,256+h*32+d] * q[n,h*32+e]  (+ col sumsq) ----------------
__global__ __launch_bounds__(256) void gram_kernel(const u16* __restrict__ qkv,
                                                   float* __restrict__ G,
                                                   float* __restrict__ norm2) {
  const int chunk = blockIdx.x;
  const int bh = blockIdx.y;
  const int b = bh >> 3, h = bh & 7;
  __shared__ float kk[32][33];
  __shared__ float qq[32][33];
  const int tid = threadIdx.x;
  const int rr = tid >> 3;
  const int c4 = (tid & 7) * 4;
  const long rowstart = (long)b * 16384 + (long)chunk * 2048;
  const u16* qp = qkv + rowstart * 512 + h * 32;
  const u16* kp = qp + 256;
  float acc0 = 0, acc1 = 0, acc2 = 0, acc3 = 0;
  float skk[4] = {0, 0, 0, 0}, sqq[4] = {0, 0, 0, 0};
  for (int t0 = 0; t0 < 2048; t0 += 32) {
    __syncthreads();
    ushort4 kv = *reinterpret_cast<const ushort4*>(kp + (long)(t0 + rr) * 512 + c4);
    ushort4 qv = *reinterpret_cast<const ushort4*>(qp + (long)(t0 + rr) * 512 + c4);
    float f;
    f = bf2f(kv.x); kk[rr][c4 + 0] = f; skk[0] += f * f;
    f = bf2f(kv.y); kk[rr][c4 + 1] = f; skk[1] += f * f;
    f = bf2f(kv.z); kk[rr][c4 + 2] = f; skk[2] += f * f;
    f = bf2f(kv.w); kk[rr][c4 + 3] = f; skk[3] += f * f;
    f = bf2f(qv.x); qq[rr][c4 + 0] = f; sqq[0] += f * f;
    f = bf2f(qv.y); qq[rr][c4 + 1] = f; sqq[1] += f * f;
    f = bf2f(qv.z); qq[rr][c4 + 2] = f; sqq[2] += f * f;
    f = bf2f(qv.w); qq[rr][c4 + 3] = f; sqq[3] += f * f;
    __syncthreads();
#pragma unroll
    for (int r = 0; r < 32; ++r) {
      const float kval = kk[r][rr];
      acc0 += kval * qq[r][c4 + 0];
      acc1 += kval * qq[r][c4 + 1];
      acc2 += kval * qq[r][c4 + 2];
      acc3 += kval * qq[r][c4 + 3];
    }
  }
  float* gp = G + ((long)bh * 32 + rr) * 32 + c4;
  atomicAdd(gp + 0, acc0); atomicAdd(gp + 1, acc1);
  atomicAdd(gp + 2, acc2); atomicAdd(gp + 3, acc3);
  // column sum-of-squares reduction (reuse LDS)
  __syncthreads();
  kk[rr][c4 + 0] = skk[0]; kk[rr][c4 + 1] = skk[1];
  kk[rr][c4 + 2] = skk[2]; kk[rr][c4 + 3] = skk[3];
  qq[rr][c4 + 0] = sqq[0]; qq[rr][c4 + 1] = sqq[1];
  qq[rr][c4 + 2] = sqq[2]; qq[rr][c4 + 3] = sqq[3];
  __syncthreads();
  if (tid < 64) {
    const int col = tid & 31;
    float s = 0.f;
    if (tid < 32) {
#pragma unroll
      for (int r2 = 0; r2 < 32; ++r2) s += kk[r2][col];
      atomicAdd(&norm2[b * 512 + 256 + h * 32 + col], s);
    } else {
#pragma unroll
      for (int r2 = 0; r2 < 32; ++r2) s += qq[r2][col];
      atomicAdd(&norm2[b * 512 + h * 32 + col], s);
    }
  }
}

// ---------------- normalize + rescale + softmax over e ----------------
__global__ void attn_softmax(const float* __restrict__ G, const float* __restrict__ norm2,
                             const float* __restrict__ rescale, float* __restrict__ attn) {
  const int bh = blockIdx.x;
  const int b = bh >> 3, h = bh & 7;
  const int t = threadIdx.x;
  __shared__ float iqs[32], iks[32];
  if (t < 32) {
    iqs[t] = 1.0f / fmaxf(sqrtf(norm2[b * 512 + h * 32 + t]), 1e-12f);
    iks[t] = 1.0f / fmaxf(sqrtf(norm2[b * 512 + 256 + h * 32 + t]), 1e-12f);
  }
  __syncthreads();
  if (t < 32) {
    const float rs = rescale[h];
    const float ikd = iks[t] * rs;
    const float* gp = G + ((long)bh * 32 + t) * 32;
    float l[32];
    float mx = -1e30f;
#pragma unroll
    for (int e = 0; e < 32; ++e) {
      l[e] = gp[e] * ikd * iqs[e];
      mx = fmaxf(mx, l[e]);
    }
    float s = 0.f;
#pragma unroll
    for (int e = 0; e < 32; ++e) {
      l[e] = expf(l[e] - mx);
      s += l[e];
    }
    const float inv = 1.0f / s;
    float* op = attn + ((long)bh * 32 + t) * 32;
#pragma unroll
    for (int e = 0; e < 32; ++e) op[e] = l[e] * inv;
  }
}

// ---------------- weff[b][c][h*32+e] = sum_d Wp[c][h*32+d]*attn[b][h][d][e]; + p1pad halo ----------------
__global__ __launch_bounds__(256) void weff_border(const float* __restrict__ Wp,
                                                   const float* __restrict__ attn,
                                                   u16* __restrict__ weff,
                                                   u16* __restrict__ p1pad) {
  const int blk = blockIdx.x;
  const int t = threadIdx.x;
  if (blk < 64) {
    __shared__ float A[32][33];
    const int b = blk >> 3, h = blk & 7;
    const float* ap = attn + (long)blk * 1024;
    for (int j = t; j < 1024; j += 256) A[j >> 5][j & 31] = ap[j];
    __syncthreads();
    const float* wrow = Wp + (long)t * 256 + h * 32;
    float w[32];
#pragma unroll
    for (int d = 0; d < 32; ++d) w[d] = wrow[d];
    u16* orow = weff + ((long)b * 256 + t) * 256 + h * 32;
#pragma unroll
    for (int e = 0; e < 32; ++e) {
      float s = 0.f;
#pragma unroll
      for (int d = 0; d < 32; ++d) s += w[d] * A[d][e];
      orow[e] = f2bf(s);
    }
  } else {
    const int idx = (blk - 64) * 256 + t;
    if (idx < 8 * 516 * 32) border_body(p1pad, idx);
  }
}

// ---------------- launch ----------------
extern "C" void kernel_launch(void* const* d_in, const int* in_sizes, int n_in,
                              void* d_out, int out_size, void* d_ws, size_t ws_size,
                              hipStream_t stream) {
  const float* x = (const float*)d_in[0];
  const float* Wq = (const float*)d_in[1];
  const float* Wk = (const float*)d_in[2];
  const float* Wv = (const float*)d_in[3];
  const float* resc = (const float*)d_in[4];
  const float* Wp = (const float*)d_in[5];
  const float* bp = (const float*)d_in[6];
  const float* Wc1 = (const float*)d_in[7];
  const float* bc1 = (const float*)d_in[8];
  const float* Wc2 = (const float*)d_in[9];
  const float* bc2 = (const float*)d_in[10];

  char* ws = (char*)d_ws;
  u16* qkv   = (u16*)(ws + 0L);            // [131072][512] q|k ; dead after gram
  u16* p1pad = (u16*)(ws + 0L);            // [8][130][130][256] conv1 out (overlays qkv)
  u16* vpad  = (u16*)(ws + 134217728L);    // [8][130][130][256] v padded
  u16* xb    = (u16*)(ws + 203440128L);    // x bf16
  u16* wqkv  = (u16*)(ws + 270548992L);    // [768][256]
  u16* wc1r  = (u16*)(ws + 270942208L);    // [256][2304]
  u16* wc2r  = (u16*)(ws + 272121856L);    // [256][2304]
  u16* weff  = (u16*)(ws + 273301504L);    // [8][256][256]
  float* norm2 = (float*)(ws + 274350080L);  // [8][512]
  float* G     = (float*)(ws + 274366464L);  // [64][32][32]
  float* attn  = (float*)(ws + 274628608L);  // [64][32][32]

  float* out_c = (float*)d_out;
  float* out_p = out_c + 33554432L;

  hipMemsetAsync(norm2, 0, 16384 + 262144, stream);

  cvt_f32_bf16<<<32768, 256, 0, stream>>>(x, xb, 8388608);
  prep<<<5316, 256, 0, stream>>>(Wq, Wk, Wv, Wc1, Wc2, wqkv, wc1r, wc2r, vpad);

  // QKV projection: q,k -> qkv[131072][512]; v -> vpad (1536 blocks, co-XCD col-tiles)
  mm8<0, 256, 0, 0, 2><<<1536, 512, 131072, stream>>>(xb, wqkv, nullptr, qkv, vpad);

  gram_kernel<<<dim3(8, 64), 256, 0, stream>>>(qkv, G, norm2);
  attn_softmax<<<64, 64, 0, stream>>>(G, norm2, resc, attn);
  weff_border<<<580, 256, 0, stream>>>(Wp, attn, weff, p1pad);

  // out_c = v @ weff[b]^T + bp   (reads vpad directly)
  mm8<2, 256, 1, 1, 0><<<512, 512, 131072, stream>>>(vpad, weff, bp, out_c, nullptr);

  // conv branch (cgroup-outer K-order for L2 locality)
  mm8<1, 2304, 2, 0, 1><<<512, 512, 131072, stream>>>(vpad, wc1r, bc1, p1pad, nullptr);
  mm8<1, 2304, 1, 0, 1><<<512, 512, 131072, stream>>>(p1pad, wc2r, bc2, out_p, nullptr);
}